// Round 1
// baseline (1552.114 us; speedup 1.0000x reference)
//
#include <hip/hip_runtime.h>

#define NN 80000
#define NE 1280000
#define NGR 8
#define BN_EPS 1e-3f

// ---------------- graph offsets from sorted ids ----------------
__global__ __launch_bounds__(256) void k_graph_off(const int* __restrict__ ids,
                                                   int* __restrict__ off) {
    int n = blockIdx.x * 256 + threadIdx.x;
    if (n >= NN) return;
    int c = ids[n];
    int p = (n == 0) ? -1 : ids[n - 1];
    for (int g = p + 1; g <= c; ++g) off[g] = n;
    if (n == NN - 1)
        for (int g = c + 1; g <= NGR; ++g) off[g] = NN;
}

// ---------------- S[n,g] = sum_{e: dst=n, ids[src]=g} ew[e] ----------------
__global__ __launch_bounds__(256) void k_S(const int* __restrict__ src,
                                           const int* __restrict__ dst,
                                           const float* __restrict__ ew,
                                           const int* __restrict__ ids,
                                           float* __restrict__ S) {
    int e = blockIdx.x * 256 + threadIdx.x;
    if (e >= NE) return;
    atomicAdd(&S[dst[e] * NGR + ids[src[e]]], ew[e]);
}

// ---------------- aggX[n,0:3] = sum ew * x[src]  (3 features) ----------------
__global__ __launch_bounds__(256) void k_scatterX(const float* __restrict__ x,
                                                  const int* __restrict__ src,
                                                  const int* __restrict__ dst,
                                                  const float* __restrict__ ew,
                                                  float* __restrict__ aggX) {
    int e = blockIdx.x * 256 + threadIdx.x;
    if (e >= NE) return;
    float w = ew[e];
    int s = src[e] * 3, d = dst[e] * 3;
    atomicAdd(&aggX[d + 0], w * x[s + 0]);
    atomicAdd(&aggX[d + 1], w * x[s + 1]);
    atomicAdd(&aggX[d + 2], w * x[s + 2]);
}

// ---------------- generic F-feature edge scatter (F = 2^LOGF) ----------------
template <int LOGF>
__global__ __launch_bounds__(256) void k_scatter(const float* __restrict__ h,
                                                 const int* __restrict__ src,
                                                 const int* __restrict__ dst,
                                                 const float* __restrict__ ew,
                                                 float* __restrict__ agg) {
    const int F = 1 << LOGF;
    unsigned int t = blockIdx.x * 256u + threadIdx.x;
    if (t >= (unsigned int)NE * F) return;
    int e = (int)(t >> LOGF);
    int f = (int)(t & (F - 1));
    float v = ew[e] * h[src[e] * F + f];
    atomicAdd(&agg[dst[e] * F + f], v);
}

// ---------------- layer1 finalize: h1 = relu(aggX @ W1 + b1) ----------------
__global__ __launch_bounds__(256) void k_l1(const float* __restrict__ aggX,
                                            const float* __restrict__ W1,
                                            const float* __restrict__ b1,
                                            float* __restrict__ h1) {
    int t = blockIdx.x * 256 + threadIdx.x;
    if (t >= NN * 32) return;
    int n = t >> 5, f = t & 31;
    float acc = b1[f];
    #pragma unroll
    for (int k = 0; k < 3; ++k) acc += aggX[n * 3 + k] * W1[k * 32 + f];
    h1[t] = fmaxf(acc, 0.f);
}

// ---------------- tmp2 = h1 @ W2  (32x32) ----------------
__global__ __launch_bounds__(256) void k_mm32(const float* __restrict__ h,
                                              const float* __restrict__ W,
                                              float* __restrict__ o) {
    int t = blockIdx.x * 256 + threadIdx.x;
    if (t >= NN * 32) return;
    int n = t >> 5, f = t & 31;
    float acc = 0.f;
    #pragma unroll
    for (int k = 0; k < 32; ++k) acc += h[n * 32 + k] * W[k * 32 + f];
    o[t] = acc;
}

// ---------------- tmp4 = h3 @ W4  (64x64) ----------------
__global__ __launch_bounds__(256) void k_mm64(const float* __restrict__ h,
                                              const float* __restrict__ W,
                                              float* __restrict__ o) {
    int t = blockIdx.x * 256 + threadIdx.x;
    if (t >= NN * 64) return;
    int n = t >> 6, f = t & 63;
    float acc = 0.f;
    #pragma unroll
    for (int k = 0; k < 64; ++k) acc += h[n * 64 + k] * W[k * 64 + f];
    o[t] = acc;
}

// ---------------- pool: MX[g,f] = max_n BN(relu(agg[n,f]+b[f])) ----------------
template <int F>
__global__ __launch_bounds__(256) void k_pool(const float* __restrict__ agg,
                                              const int* __restrict__ off,
                                              const float* __restrict__ b,
                                              const float* __restrict__ g,
                                              const float* __restrict__ be,
                                              const float* __restrict__ m,
                                              const float* __restrict__ v,
                                              float* __restrict__ mx) {
    const int ROWS = 256 / F;
    __shared__ float red[256];
    int gid = blockIdx.x;
    int f = threadIdx.x & (F - 1);
    int r = threadIdx.x / F;
    int n0 = off[gid], n1 = off[gid + 1];
    float scale = g[f] * rsqrtf(v[f] + BN_EPS);
    float bias = b[f], mm = m[f], bee = be[f];
    float acc = -INFINITY;
    for (int n = n0 + r; n < n1; n += ROWS) {
        float h = fmaxf(agg[n * F + f] + bias, 0.f);
        acc = fmaxf(acc, (h - mm) * scale + bee);
    }
    red[threadIdx.x] = acc;
    __syncthreads();
    for (int s = ROWS / 2; s > 0; s >>= 1) {
        if (r < s) red[r * F + f] = fmaxf(red[r * F + f], red[(r + s) * F + f]);
        __syncthreads();
    }
    if (r == 0) mx[gid * F + f] = (n1 > n0) ? red[f] : 0.f;
}

// ---------------- HW3 = MX1 @ W3  (8x32 @ 32x64), one block 512 ----------------
__global__ __launch_bounds__(512) void k_hw3(const float* __restrict__ MX,
                                             const float* __restrict__ W,
                                             float* __restrict__ HW) {
    int t = threadIdx.x;  // 512
    int g = t >> 6, f = t & 63;
    float acc = 0.f;
    #pragma unroll
    for (int k = 0; k < 32; ++k) acc += MX[g * 32 + k] * W[k * 64 + f];
    HW[t] = acc;
}

// ---------------- HW5 = MX2 @ W5  (8x64 @ 64x20), one block ----------------
__global__ __launch_bounds__(256) void k_hw5(const float* __restrict__ MX,
                                             const float* __restrict__ W,
                                             float* __restrict__ HW) {
    int t = threadIdx.x;
    if (t >= 160) return;
    int g = t / 20, c = t % 20;
    float acc = 0.f;
    #pragma unroll
    for (int k = 0; k < 64; ++k) acc += MX[g * 64 + k] * W[k * 20 + c];
    HW[t] = acc;
}

// ---------------- h3 = relu(S @ HW3 + b3)  [N,64] ----------------
__global__ __launch_bounds__(256) void k_l3(const float* __restrict__ S,
                                            const float* __restrict__ HW,
                                            const float* __restrict__ b,
                                            float* __restrict__ h3) {
    int t = blockIdx.x * 256 + threadIdx.x;
    if (t >= NN * 64) return;
    int n = t >> 6, f = t & 63;
    float acc = b[f];
    #pragma unroll
    for (int g = 0; g < NGR; ++g) acc += S[n * NGR + g] * HW[g * 64 + f];
    h3[t] = fmaxf(acc, 0.f);
}

// ---------------- out = softmax(S @ HW5 + b5)  [N,20] ----------------
__global__ __launch_bounds__(256) void k_out(const float* __restrict__ S,
                                             const float* __restrict__ HW5,
                                             const float* __restrict__ b5,
                                             float* __restrict__ out) {
    __shared__ float hw[160];
    __shared__ float bb[20];
    int t = threadIdx.x;
    if (t < 160) hw[t] = HW5[t];
    if (t < 20) bb[t] = b5[t];
    __syncthreads();
    int n = blockIdx.x * 256 + t;
    if (n >= NN) return;
    const float4* sp = (const float4*)(S + n * 8);
    float4 s0 = sp[0], s1 = sp[1];
    float sv[8] = {s0.x, s0.y, s0.z, s0.w, s1.x, s1.y, s1.z, s1.w};
    float pre[20];
    #pragma unroll
    for (int c = 0; c < 20; ++c) {
        float acc = bb[c];
        #pragma unroll
        for (int g = 0; g < 8; ++g) acc += sv[g] * hw[g * 20 + c];
        pre[c] = acc;
    }
    float mx = pre[0];
    #pragma unroll
    for (int c = 1; c < 20; ++c) mx = fmaxf(mx, pre[c]);
    float sum = 0.f;
    #pragma unroll
    for (int c = 0; c < 20; ++c) { pre[c] = __expf(pre[c] - mx); sum += pre[c]; }
    float inv = 1.f / sum;
    #pragma unroll
    for (int c = 0; c < 20; ++c) out[n * 20 + c] = pre[c] * inv;
}

extern "C" void kernel_launch(void* const* d_in, const int* in_sizes, int n_in,
                              void* d_out, int out_size, void* d_ws, size_t ws_size,
                              hipStream_t stream) {
    const float* x   = (const float*)d_in[0];
    const float* ew  = (const float*)d_in[1];
    const int*   src = (const int*)d_in[2];
    const int*   dst = (const int*)d_in[3];
    const int*   ids = (const int*)d_in[4];
    const float* W1 = (const float*)d_in[5];  const float* b1 = (const float*)d_in[6];
    const float* W2 = (const float*)d_in[7];  const float* b2 = (const float*)d_in[8];
    const float* g1 = (const float*)d_in[9];  const float* be1 = (const float*)d_in[10];
    const float* m1 = (const float*)d_in[11]; const float* v1 = (const float*)d_in[12];
    const float* W3 = (const float*)d_in[13]; const float* b3 = (const float*)d_in[14];
    const float* W4 = (const float*)d_in[15]; const float* b4 = (const float*)d_in[16];
    const float* g2 = (const float*)d_in[17]; const float* be2 = (const float*)d_in[18];
    const float* m2 = (const float*)d_in[19]; const float* v2 = (const float*)d_in[20];
    const float* W5 = (const float*)d_in[21]; const float* b5 = (const float*)d_in[22];
    float* out = (float*)d_out;

    // workspace layout (all 256B-aligned sizes)
    char* p = (char*)d_ws;
    float* S  = (float*)p; p += (size_t)NN * 8 * 4;    // 2.56 MB, live whole run
    float* A  = (float*)p; p += (size_t)NN * 64 * 4;   // aggX / tmp2 / tmp4
    float* B  = (float*)p; p += (size_t)NN * 64 * 4;   // h1 / h3
    float* C  = (float*)p; p += (size_t)NN * 64 * 4;   // agg2 / agg4
    float* MX1 = (float*)p; p += 256 * 4;
    float* HW3 = (float*)p; p += 512 * 4;
    float* MX2 = (float*)p; p += 512 * 4;
    float* HW5 = (float*)p; p += 256 * 4;
    int*   off = (int*)p;  p += 64 * 4;

    const int BS = 256;
    const int gE  = (NE + BS - 1) / BS;
    const int gN  = (NN + BS - 1) / BS;

    // graph offsets + S (independent of layer pipeline)
    hipLaunchKernelGGL(k_graph_off, dim3(gN), dim3(BS), 0, stream, ids, off);
    hipMemsetAsync(S, 0, (size_t)NN * 8 * 4, stream);
    hipLaunchKernelGGL(k_S, dim3(gE), dim3(BS), 0, stream, src, dst, ew, ids, S);

    // layer 1: scatter x (3 feats) then dense W1
    hipMemsetAsync(A, 0, (size_t)NN * 3 * 4, stream);
    hipLaunchKernelGGL(k_scatterX, dim3(gE), dim3(BS), 0, stream, x, src, dst, ew, A);
    hipLaunchKernelGGL(k_l1, dim3(NN * 32 / BS), dim3(BS), 0, stream, A, W1, b1, B);

    // layer 2: tmp2 = h1@W2, scatter 32, pool(+relu+BN) -> MX1
    hipLaunchKernelGGL(k_mm32, dim3(NN * 32 / BS), dim3(BS), 0, stream, B, W2, A);
    hipMemsetAsync(C, 0, (size_t)NN * 32 * 4, stream);
    hipLaunchKernelGGL(k_scatter<5>, dim3(NE * 32 / BS), dim3(BS), 0, stream, A, src, dst, ew, C);
    hipLaunchKernelGGL(k_pool<32>, dim3(NGR), dim3(BS), 0, stream, C, off, b2, g1, be1, m1, v1, MX1);

    // layer 3 (collapsed): HW3 = MX1@W3; h3 = relu(S@HW3 + b3)
    hipLaunchKernelGGL(k_hw3, dim3(1), dim3(512), 0, stream, MX1, W3, HW3);
    hipLaunchKernelGGL(k_l3, dim3(NN * 64 / BS), dim3(BS), 0, stream, S, HW3, b3, B);

    // layer 4: tmp4 = h3@W4, scatter 64, pool(+relu+BN) -> MX2
    hipLaunchKernelGGL(k_mm64, dim3(NN * 64 / BS), dim3(BS), 0, stream, B, W4, A);
    hipMemsetAsync(C, 0, (size_t)NN * 64 * 4, stream);
    hipLaunchKernelGGL(k_scatter<6>, dim3(NE * 64 / BS), dim3(BS), 0, stream, A, src, dst, ew, C);
    hipLaunchKernelGGL(k_pool<64>, dim3(NGR), dim3(BS), 0, stream, C, off, b4, g2, be2, m2, v2, MX2);

    // layer 5 (collapsed): HW5 = MX2@W5; out = softmax(S@HW5 + b5)
    hipLaunchKernelGGL(k_hw5, dim3(1), dim3(BS), 0, stream, MX2, W5, HW5);
    hipLaunchKernelGGL(k_out, dim3(gN), dim3(BS), 0, stream, S, HW5, b5, out);
}

// Round 2
// 980.543 us; speedup vs baseline: 1.5829x; 1.5829x over previous
//
#include <hip/hip_runtime.h>

#define NN 80000
#define NE 1280000
#define NGR 8
#define BN_EPS 1e-3f

// ---------------- order-preserving float <-> unsigned encoding ----------------
__device__ __forceinline__ unsigned enc_f(float f) {
    unsigned b = __float_as_uint(f);
    return (f >= 0.f) ? (b | 0x80000000u) : ~b;
}
__device__ __forceinline__ float dec_f(unsigned u) {
    return (u & 0x80000000u) ? __uint_as_float(u & 0x7FFFFFFFu) : __uint_as_float(~u);
}

// ---------------- S[n,g] = sum_{e: dst=n, ids[src]=g} ew[e] ----------------
__global__ __launch_bounds__(256) void k_S(const int* __restrict__ src,
                                           const int* __restrict__ dst,
                                           const float* __restrict__ ew,
                                           const int* __restrict__ ids,
                                           float* __restrict__ S) {
    int e = blockIdx.x * 256 + threadIdx.x;
    if (e >= NE) return;
    atomicAdd(&S[dst[e] * NGR + ids[src[e]]], ew[e]);
}

// ---------------- aggX[n,0:3] = sum ew * x[src]  (3 features) ----------------
__global__ __launch_bounds__(256) void k_scatterX(const float* __restrict__ x,
                                                  const int* __restrict__ src,
                                                  const int* __restrict__ dst,
                                                  const float* __restrict__ ew,
                                                  float* __restrict__ aggX) {
    int e = blockIdx.x * 256 + threadIdx.x;
    if (e >= NE) return;
    float w = ew[e];
    int s = src[e] * 3, d = dst[e] * 3;
    atomicAdd(&aggX[d + 0], w * x[s + 0]);
    atomicAdd(&aggX[d + 1], w * x[s + 1]);
    atomicAdd(&aggX[d + 2], w * x[s + 2]);
}

// ---------------- generic F-feature edge scatter (F = 2^LOGF) ----------------
template <int LOGF>
__global__ __launch_bounds__(256) void k_scatter(const float* __restrict__ h,
                                                 const int* __restrict__ src,
                                                 const int* __restrict__ dst,
                                                 const float* __restrict__ ew,
                                                 float* __restrict__ agg) {
    const int F = 1 << LOGF;
    unsigned int t = blockIdx.x * 256u + threadIdx.x;
    if (t >= (unsigned int)NE * F) return;
    int e = (int)(t >> LOGF);
    int f = (int)(t & (F - 1));
    float v = ew[e] * h[src[e] * F + f];
    atomicAdd(&agg[dst[e] * F + f], v);
}

// ---------------- layer1 finalize: h1 = relu(aggX @ W1 + b1) ----------------
__global__ __launch_bounds__(256) void k_l1(const float* __restrict__ aggX,
                                            const float* __restrict__ W1,
                                            const float* __restrict__ b1,
                                            float* __restrict__ h1) {
    int t = blockIdx.x * 256 + threadIdx.x;
    if (t >= NN * 32) return;
    int n = t >> 5, f = t & 31;
    float acc = b1[f];
    #pragma unroll
    for (int k = 0; k < 3; ++k) acc += aggX[n * 3 + k] * W1[k * 32 + f];
    h1[t] = fmaxf(acc, 0.f);
}

// ---------------- tmp2 = h1 @ W2  (32x32) ----------------
__global__ __launch_bounds__(256) void k_mm32(const float* __restrict__ h,
                                              const float* __restrict__ W,
                                              float* __restrict__ o) {
    int t = blockIdx.x * 256 + threadIdx.x;
    if (t >= NN * 32) return;
    int n = t >> 5, f = t & 31;
    float acc = 0.f;
    #pragma unroll
    for (int k = 0; k < 32; ++k) acc += h[n * 32 + k] * W[k * 32 + f];
    o[t] = acc;
}

// ---------------- tmp4 = h3 @ W4  (64x64) ----------------
__global__ __launch_bounds__(256) void k_mm64(const float* __restrict__ h,
                                              const float* __restrict__ W,
                                              float* __restrict__ o) {
    int t = blockIdx.x * 256 + threadIdx.x;
    if (t >= NN * 64) return;
    int n = t >> 6, f = t & 63;
    float acc = 0.f;
    #pragma unroll
    for (int k = 0; k < 64; ++k) acc += h[n * 64 + k] * W[k * 64 + f];
    o[t] = acc;
}

// ---- pool stage 1: node-parallel, per-thread running max, atomicMax flush ----
// NPB nodes per block; ids sorted so each thread's graph id is non-decreasing.
template <int LOGF, int NPB>
__global__ __launch_bounds__(256) void k_pool2(const float* __restrict__ agg,
                                               const int* __restrict__ ids,
                                               const float* __restrict__ b,
                                               const float* __restrict__ g,
                                               const float* __restrict__ be,
                                               const float* __restrict__ m,
                                               const float* __restrict__ v,
                                               unsigned* __restrict__ mxe) {
    const int F = 1 << LOGF;
    const int ROWS = 256 >> LOGF;
    int f = threadIdx.x & (F - 1);
    int r = threadIdx.x >> LOGF;
    int n0 = blockIdx.x * NPB;
    int n1 = min(n0 + NPB, NN);
    float scale = g[f] * rsqrtf(v[f] + BN_EPS);
    float bias = b[f], mm = m[f], bee = be[f];
    int curg = -1;
    float cur = -INFINITY;
    for (int n = n0 + r; n < n1; n += ROWS) {
        int gg = ids[n];
        if (gg != curg) {
            if (curg >= 0) atomicMax(&mxe[curg * F + f], enc_f(cur));
            curg = gg;
            cur = -INFINITY;
        }
        float h = fmaxf(agg[n * F + f] + bias, 0.f);
        cur = fmaxf(cur, (h - mm) * scale + bee);
    }
    if (curg >= 0) atomicMax(&mxe[curg * F + f], enc_f(cur));
}

// ---- pool stage 2: decode encoded max back to float (0 sentinel -> 0.0) ----
template <int F>
__global__ __launch_bounds__(512) void k_dec(const unsigned* __restrict__ mxe,
                                             float* __restrict__ mx) {
    int t = threadIdx.x;
    if (t < NGR * F) mx[t] = mxe[t] ? dec_f(mxe[t]) : 0.f;
}

// ---------------- HW3 = MX1 @ W3  (8x32 @ 32x64), one block 512 ----------------
__global__ __launch_bounds__(512) void k_hw3(const float* __restrict__ MX,
                                             const float* __restrict__ W,
                                             float* __restrict__ HW) {
    int t = threadIdx.x;  // 512
    int g = t >> 6, f = t & 63;
    float acc = 0.f;
    #pragma unroll
    for (int k = 0; k < 32; ++k) acc += MX[g * 32 + k] * W[k * 64 + f];
    HW[t] = acc;
}

// ---------------- HW5 = MX2 @ W5  (8x64 @ 64x20), one block ----------------
__global__ __launch_bounds__(256) void k_hw5(const float* __restrict__ MX,
                                             const float* __restrict__ W,
                                             float* __restrict__ HW) {
    int t = threadIdx.x;
    if (t >= 160) return;
    int g = t / 20, c = t % 20;
    float acc = 0.f;
    #pragma unroll
    for (int k = 0; k < 64; ++k) acc += MX[g * 64 + k] * W[k * 20 + c];
    HW[t] = acc;
}

// ---------------- h3 = relu(S @ HW3 + b3)  [N,64] ----------------
__global__ __launch_bounds__(256) void k_l3(const float* __restrict__ S,
                                            const float* __restrict__ HW,
                                            const float* __restrict__ b,
                                            float* __restrict__ h3) {
    int t = blockIdx.x * 256 + threadIdx.x;
    if (t >= NN * 64) return;
    int n = t >> 6, f = t & 63;
    float acc = b[f];
    #pragma unroll
    for (int g = 0; g < NGR; ++g) acc += S[n * NGR + g] * HW[g * 64 + f];
    h3[t] = fmaxf(acc, 0.f);
}

// ---------------- out = softmax(S @ HW5 + b5)  [N,20] ----------------
__global__ __launch_bounds__(256) void k_out(const float* __restrict__ S,
                                             const float* __restrict__ HW5,
                                             const float* __restrict__ b5,
                                             float* __restrict__ out) {
    __shared__ float hw[160];
    __shared__ float bb[20];
    int t = threadIdx.x;
    if (t < 160) hw[t] = HW5[t];
    if (t < 20) bb[t] = b5[t];
    __syncthreads();
    int n = blockIdx.x * 256 + t;
    if (n >= NN) return;
    const float4* sp = (const float4*)(S + n * 8);
    float4 s0 = sp[0], s1 = sp[1];
    float sv[8] = {s0.x, s0.y, s0.z, s0.w, s1.x, s1.y, s1.z, s1.w};
    float pre[20];
    #pragma unroll
    for (int c = 0; c < 20; ++c) {
        float acc = bb[c];
        #pragma unroll
        for (int g = 0; g < 8; ++g) acc += sv[g] * hw[g * 20 + c];
        pre[c] = acc;
    }
    float mx = pre[0];
    #pragma unroll
    for (int c = 1; c < 20; ++c) mx = fmaxf(mx, pre[c]);
    float sum = 0.f;
    #pragma unroll
    for (int c = 0; c < 20; ++c) { pre[c] = __expf(pre[c] - mx); sum += pre[c]; }
    float inv = 1.f / sum;
    #pragma unroll
    for (int c = 0; c < 20; ++c) out[n * 20 + c] = pre[c] * inv;
}

extern "C" void kernel_launch(void* const* d_in, const int* in_sizes, int n_in,
                              void* d_out, int out_size, void* d_ws, size_t ws_size,
                              hipStream_t stream) {
    const float* x   = (const float*)d_in[0];
    const float* ew  = (const float*)d_in[1];
    const int*   src = (const int*)d_in[2];
    const int*   dst = (const int*)d_in[3];
    const int*   ids = (const int*)d_in[4];
    const float* W1 = (const float*)d_in[5];  const float* b1 = (const float*)d_in[6];
    const float* W2 = (const float*)d_in[7];  const float* b2 = (const float*)d_in[8];
    const float* g1 = (const float*)d_in[9];  const float* be1 = (const float*)d_in[10];
    const float* m1 = (const float*)d_in[11]; const float* v1 = (const float*)d_in[12];
    const float* W3 = (const float*)d_in[13]; const float* b3 = (const float*)d_in[14];
    const float* W4 = (const float*)d_in[15]; const float* b4 = (const float*)d_in[16];
    const float* g2 = (const float*)d_in[17]; const float* be2 = (const float*)d_in[18];
    const float* m2 = (const float*)d_in[19]; const float* v2 = (const float*)d_in[20];
    const float* W5 = (const float*)d_in[21]; const float* b5 = (const float*)d_in[22];
    float* out = (float*)d_out;

    // workspace layout
    char* p = (char*)d_ws;
    float* S  = (float*)p; p += (size_t)NN * 8 * 4;    // live whole run
    float* A  = (float*)p; p += (size_t)NN * 64 * 4;   // aggX / tmp2 / tmp4
    float* B  = (float*)p; p += (size_t)NN * 64 * 4;   // h1 / h3
    float* C  = (float*)p; p += (size_t)NN * 64 * 4;   // agg2 / agg4
    unsigned* MXE = (unsigned*)p; p += 512 * 4;        // encoded pool max
    float* MX1 = (float*)p; p += 256 * 4;
    float* HW3 = (float*)p; p += 512 * 4;
    float* MX2 = (float*)p; p += 512 * 4;
    float* HW5 = (float*)p; p += 256 * 4;

    const int BS = 256;
    const int gE = (NE + BS - 1) / BS;
    const int gN = (NN + BS - 1) / BS;
    const int NPB = 128;
    const int gP = (NN + NPB - 1) / NPB;

    // S matrix (independent of layer pipeline)
    hipMemsetAsync(S, 0, (size_t)NN * 8 * 4, stream);
    hipLaunchKernelGGL(k_S, dim3(gE), dim3(BS), 0, stream, src, dst, ew, ids, S);

    // layer 1: scatter x (3 feats) then dense W1
    hipMemsetAsync(A, 0, (size_t)NN * 3 * 4, stream);
    hipLaunchKernelGGL(k_scatterX, dim3(gE), dim3(BS), 0, stream, x, src, dst, ew, A);
    hipLaunchKernelGGL(k_l1, dim3(NN * 32 / BS), dim3(BS), 0, stream, A, W1, b1, B);

    // layer 2: tmp2 = h1@W2, scatter 32, pool(+relu+BN) -> MX1
    hipLaunchKernelGGL(k_mm32, dim3(NN * 32 / BS), dim3(BS), 0, stream, B, W2, A);
    hipMemsetAsync(C, 0, (size_t)NN * 32 * 4, stream);
    hipLaunchKernelGGL(k_scatter<5>, dim3(NE * 32 / BS), dim3(BS), 0, stream, A, src, dst, ew, C);
    hipMemsetAsync(MXE, 0, 512 * 4, stream);
    hipLaunchKernelGGL((k_pool2<5, NPB>), dim3(gP), dim3(BS), 0, stream, C, ids, b2, g1, be1, m1, v1, MXE);
    hipLaunchKernelGGL(k_dec<32>, dim3(1), dim3(512), 0, stream, MXE, MX1);

    // layer 3 (collapsed): HW3 = MX1@W3; h3 = relu(S@HW3 + b3)
    hipLaunchKernelGGL(k_hw3, dim3(1), dim3(512), 0, stream, MX1, W3, HW3);
    hipLaunchKernelGGL(k_l3, dim3(NN * 64 / BS), dim3(BS), 0, stream, S, HW3, b3, B);

    // layer 4: tmp4 = h3@W4, scatter 64, pool(+relu+BN) -> MX2
    hipLaunchKernelGGL(k_mm64, dim3(NN * 64 / BS), dim3(BS), 0, stream, B, W4, A);
    hipMemsetAsync(C, 0, (size_t)NN * 64 * 4, stream);
    hipLaunchKernelGGL(k_scatter<6>, dim3(NE * 64 / BS), dim3(BS), 0, stream, A, src, dst, ew, C);
    hipMemsetAsync(MXE, 0, 512 * 4, stream);
    hipLaunchKernelGGL((k_pool2<6, NPB>), dim3(gP), dim3(BS), 0, stream, C, ids, b4, g2, be2, m2, v2, MXE);
    hipLaunchKernelGGL(k_dec<64>, dim3(1), dim3(512), 0, stream, MXE, MX2);

    // layer 5 (collapsed): HW5 = MX2@W5; out = softmax(S@HW5 + b5)
    hipLaunchKernelGGL(k_hw5, dim3(1), dim3(BS), 0, stream, MX2, W5, HW5);
    hipLaunchKernelGGL(k_out, dim3(gN), dim3(BS), 0, stream, S, HW5, b5, out);
}

// Round 3
// 682.099 us; speedup vs baseline: 2.2755x; 1.4375x over previous
//
#include <hip/hip_runtime.h>

#define NN 80000
#define NE 1280000
#define NGR 8
#define BN_EPS 1e-3f
#define NBL_SCAN 313   // ceil(NN/256)

// ---------------- order-preserving float <-> unsigned encoding ----------------
__device__ __forceinline__ unsigned enc_f(float f) {
    unsigned b = __float_as_uint(f);
    return (f >= 0.f) ? (b | 0x80000000u) : ~b;
}
__device__ __forceinline__ float dec_f(unsigned u) {
    return (u & 0x80000000u) ? __uint_as_float(u & 0x7FFFFFFFu) : __uint_as_float(~u);
}

// ================= CSR build =================
__global__ __launch_bounds__(256) void k_hist(const int* __restrict__ dst,
                                              int* __restrict__ cnt) {
    int e = blockIdx.x * 256 + threadIdx.x;
    if (e >= NE) return;
    atomicAdd(&cnt[dst[e]], 1);
}

// per-256-chunk exclusive scan; chunk sums to parts[]
__global__ __launch_bounds__(256) void k_scanA(const int* __restrict__ cnt,
                                               int* __restrict__ rp,
                                               int* __restrict__ parts) {
    __shared__ int sm[256];
    int tid = threadIdx.x;
    int i = blockIdx.x * 256 + tid;
    int v = (i < NN) ? cnt[i] : 0;
    sm[tid] = v;
    __syncthreads();
    #pragma unroll
    for (int off = 1; off < 256; off <<= 1) {
        int t2 = (tid >= off) ? sm[tid - off] : 0;
        __syncthreads();
        sm[tid] += t2;
        __syncthreads();
    }
    if (i < NN) rp[i] = sm[tid] - v;       // exclusive within chunk
    if (tid == 255) parts[blockIdx.x] = sm[255];
}

// one block: exclusive scan of NBL_SCAN partials (512 >= 313)
__global__ __launch_bounds__(512) void k_scanB(int* __restrict__ parts) {
    __shared__ int sm[512];
    int tid = threadIdx.x;
    int v = (tid < NBL_SCAN) ? parts[tid] : 0;
    sm[tid] = v;
    __syncthreads();
    #pragma unroll
    for (int off = 1; off < 512; off <<= 1) {
        int t2 = (tid >= off) ? sm[tid - off] : 0;
        __syncthreads();
        sm[tid] += t2;
        __syncthreads();
    }
    if (tid < NBL_SCAN) parts[tid] = sm[tid] - v;   // exclusive
}

__global__ __launch_bounds__(256) void k_scanC(int* __restrict__ rp,
                                               const int* __restrict__ parts) {
    int i = blockIdx.x * 256 + threadIdx.x;
    if (i < NN) rp[i] += parts[blockIdx.x];
    if (i == 0) rp[NN] = NE;
}

// fill CSR: csrc packs src | (graph_of_src << 24); cw = edge weight
__global__ __launch_bounds__(256) void k_fill(const int* __restrict__ src,
                                              const int* __restrict__ dst,
                                              const float* __restrict__ ew,
                                              const int* __restrict__ ids,
                                              const int* __restrict__ rp,
                                              int* __restrict__ cnt2,
                                              int* __restrict__ csrc,
                                              float* __restrict__ cw) {
    int e = blockIdx.x * 256 + threadIdx.x;
    if (e >= NE) return;
    int d = dst[e];
    int s = src[e];
    int pos = rp[d] + atomicAdd(&cnt2[d], 1);
    csrc[pos] = s | (ids[s] << 24);
    cw[pos] = ew[e];
}

// ================= gathers =================
// S[n,g] = sum of w over in-edges whose src-graph == g
__global__ __launch_bounds__(256) void k_gS(const int* __restrict__ rp,
                                            const int* __restrict__ csrc,
                                            const float* __restrict__ cw,
                                            float* __restrict__ S) {
    int t = blockIdx.x * 256 + threadIdx.x;   // NN*8 threads
    int n = t >> 3, g = t & 7;
    int e0 = rp[n], e1 = rp[n + 1];
    float acc = 0.f;
    for (int i = e0; i < e1; ++i)
        acc += ((csrc[i] >> 24) == g) ? cw[i] : 0.f;
    S[t] = acc;
}

// aggX[n, 0:4) padded; f<3 real
__global__ __launch_bounds__(256) void k_gX(const float* __restrict__ x,
                                            const int* __restrict__ rp,
                                            const int* __restrict__ csrc,
                                            const float* __restrict__ cw,
                                            float* __restrict__ aggX) {
    int t = blockIdx.x * 256 + threadIdx.x;   // NN*4 threads
    int n = t >> 2, f = t & 3;
    int e0 = rp[n], e1 = rp[n + 1];
    float acc = 0.f;
    if (f < 3)
        for (int i = e0; i < e1; ++i)
            acc += cw[i] * x[(csrc[i] & 0xFFFFFF) * 3 + f];
    aggX[t] = acc;
}

// generic F-feature gather (F = 2^LOGF)
template <int LOGF>
__global__ __launch_bounds__(256) void k_gather(const float* __restrict__ h,
                                                const int* __restrict__ rp,
                                                const int* __restrict__ csrc,
                                                const float* __restrict__ cw,
                                                float* __restrict__ agg) {
    int t = blockIdx.x * 256 + threadIdx.x;   // NN*F threads
    int n = t >> LOGF, f = t & ((1 << LOGF) - 1);
    int e0 = rp[n], e1 = rp[n + 1];
    float acc = 0.f;
    for (int i = e0; i < e1; ++i)
        acc += cw[i] * h[((csrc[i] & 0xFFFFFF) << LOGF) + f];
    agg[t] = acc;
}

// ================= dense layers =================
// h1 = relu(aggX @ W1 + b1), aggX stride 4
__global__ __launch_bounds__(256) void k_l1(const float* __restrict__ aggX,
                                            const float* __restrict__ W1,
                                            const float* __restrict__ b1,
                                            float* __restrict__ h1) {
    int t = blockIdx.x * 256 + threadIdx.x;
    int n = t >> 5, f = t & 31;
    float acc = b1[f];
    #pragma unroll
    for (int k = 0; k < 3; ++k) acc += aggX[n * 4 + k] * W1[k * 32 + f];
    h1[t] = fmaxf(acc, 0.f);
}

__global__ __launch_bounds__(256) void k_mm32(const float* __restrict__ h,
                                              const float* __restrict__ W,
                                              float* __restrict__ o) {
    int t = blockIdx.x * 256 + threadIdx.x;
    int n = t >> 5, f = t & 31;
    float acc = 0.f;
    #pragma unroll
    for (int k = 0; k < 32; ++k) acc += h[n * 32 + k] * W[k * 32 + f];
    o[t] = acc;
}

__global__ __launch_bounds__(256) void k_mm64(const float* __restrict__ h,
                                              const float* __restrict__ W,
                                              float* __restrict__ o) {
    int t = blockIdx.x * 256 + threadIdx.x;
    int n = t >> 6, f = t & 63;
    float acc = 0.f;
    #pragma unroll
    for (int k = 0; k < 64; ++k) acc += h[n * 64 + k] * W[k * 64 + f];
    o[t] = acc;
}

// ---- pool stage 1: node-parallel, running max per thread, atomicMax flush ----
template <int LOGF, int NPB>
__global__ __launch_bounds__(256) void k_pool2(const float* __restrict__ agg,
                                               const int* __restrict__ ids,
                                               const float* __restrict__ b,
                                               const float* __restrict__ g,
                                               const float* __restrict__ be,
                                               const float* __restrict__ m,
                                               const float* __restrict__ v,
                                               unsigned* __restrict__ mxe) {
    const int F = 1 << LOGF;
    const int ROWS = 256 >> LOGF;
    int f = threadIdx.x & (F - 1);
    int r = threadIdx.x >> LOGF;
    int n0 = blockIdx.x * NPB;
    int n1 = min(n0 + NPB, NN);
    float scale = g[f] * rsqrtf(v[f] + BN_EPS);
    float bias = b[f], mm = m[f], bee = be[f];
    int curg = -1;
    float cur = -INFINITY;
    for (int n = n0 + r; n < n1; n += ROWS) {
        int gg = ids[n];
        if (gg != curg) {
            if (curg >= 0) atomicMax(&mxe[curg * F + f], enc_f(cur));
            curg = gg;
            cur = -INFINITY;
        }
        float h = fmaxf(agg[n * F + f] + bias, 0.f);
        cur = fmaxf(cur, (h - mm) * scale + bee);
    }
    if (curg >= 0) atomicMax(&mxe[curg * F + f], enc_f(cur));
}

template <int F>
__global__ __launch_bounds__(512) void k_dec(const unsigned* __restrict__ mxe,
                                             float* __restrict__ mx) {
    int t = threadIdx.x;
    if (t < NGR * F) mx[t] = mxe[t] ? dec_f(mxe[t]) : 0.f;
}

__global__ __launch_bounds__(512) void k_hw3(const float* __restrict__ MX,
                                             const float* __restrict__ W,
                                             float* __restrict__ HW) {
    int t = threadIdx.x;
    int g = t >> 6, f = t & 63;
    float acc = 0.f;
    #pragma unroll
    for (int k = 0; k < 32; ++k) acc += MX[g * 32 + k] * W[k * 64 + f];
    HW[t] = acc;
}

__global__ __launch_bounds__(256) void k_hw5(const float* __restrict__ MX,
                                             const float* __restrict__ W,
                                             float* __restrict__ HW) {
    int t = threadIdx.x;
    if (t >= 160) return;
    int g = t / 20, c = t % 20;
    float acc = 0.f;
    #pragma unroll
    for (int k = 0; k < 64; ++k) acc += MX[g * 64 + k] * W[k * 20 + c];
    HW[t] = acc;
}

__global__ __launch_bounds__(256) void k_l3(const float* __restrict__ S,
                                            const float* __restrict__ HW,
                                            const float* __restrict__ b,
                                            float* __restrict__ h3) {
    int t = blockIdx.x * 256 + threadIdx.x;
    int n = t >> 6, f = t & 63;
    float acc = b[f];
    #pragma unroll
    for (int g = 0; g < NGR; ++g) acc += S[n * NGR + g] * HW[g * 64 + f];
    h3[t] = fmaxf(acc, 0.f);
}

__global__ __launch_bounds__(256) void k_out(const float* __restrict__ S,
                                             const float* __restrict__ HW5,
                                             const float* __restrict__ b5,
                                             float* __restrict__ out) {
    __shared__ float hw[160];
    __shared__ float bb[20];
    int t = threadIdx.x;
    if (t < 160) hw[t] = HW5[t];
    if (t < 20) bb[t] = b5[t];
    __syncthreads();
    int n = blockIdx.x * 256 + t;
    if (n >= NN) return;
    const float4* sp = (const float4*)(S + n * 8);
    float4 s0 = sp[0], s1 = sp[1];
    float sv[8] = {s0.x, s0.y, s0.z, s0.w, s1.x, s1.y, s1.z, s1.w};
    float pre[20];
    #pragma unroll
    for (int c = 0; c < 20; ++c) {
        float acc = bb[c];
        #pragma unroll
        for (int g = 0; g < 8; ++g) acc += sv[g] * hw[g * 20 + c];
        pre[c] = acc;
    }
    float mx = pre[0];
    #pragma unroll
    for (int c = 1; c < 20; ++c) mx = fmaxf(mx, pre[c]);
    float sum = 0.f;
    #pragma unroll
    for (int c = 0; c < 20; ++c) { pre[c] = __expf(pre[c] - mx); sum += pre[c]; }
    float inv = 1.f / sum;
    #pragma unroll
    for (int c = 0; c < 20; ++c) out[n * 20 + c] = pre[c] * inv;
}

extern "C" void kernel_launch(void* const* d_in, const int* in_sizes, int n_in,
                              void* d_out, int out_size, void* d_ws, size_t ws_size,
                              hipStream_t stream) {
    const float* x   = (const float*)d_in[0];
    const float* ew  = (const float*)d_in[1];
    const int*   src = (const int*)d_in[2];
    const int*   dst = (const int*)d_in[3];
    const int*   ids = (const int*)d_in[4];
    const float* W1 = (const float*)d_in[5];  const float* b1 = (const float*)d_in[6];
    const float* W2 = (const float*)d_in[7];  const float* b2 = (const float*)d_in[8];
    const float* g1 = (const float*)d_in[9];  const float* be1 = (const float*)d_in[10];
    const float* m1 = (const float*)d_in[11]; const float* v1 = (const float*)d_in[12];
    const float* W3 = (const float*)d_in[13]; const float* b3 = (const float*)d_in[14];
    const float* W4 = (const float*)d_in[15]; const float* b4 = (const float*)d_in[16];
    const float* g2 = (const float*)d_in[17]; const float* be2 = (const float*)d_in[18];
    const float* m2 = (const float*)d_in[19]; const float* v2 = (const float*)d_in[20];
    const float* W5 = (const float*)d_in[21]; const float* b5 = (const float*)d_in[22];
    float* out = (float*)d_out;

    // workspace layout (~56 MB)
    char* p = (char*)d_ws;
    float* S    = (float*)p; p += (size_t)NN * 8 * 4;
    float* A    = (float*)p; p += (size_t)NN * 64 * 4;
    float* B    = (float*)p; p += (size_t)NN * 64 * 4;
    float* AX   = (float*)p; p += (size_t)NN * 4 * 4;
    int*   rp   = (int*)p;   p += (size_t)(NN + 1) * 4;
    int*   cnt  = (int*)p;   p += (size_t)NN * 4;
    int*   cnt2 = (int*)p;   p += (size_t)NN * 4;
    int*   parts= (int*)p;   p += 512 * 4;
    int*   csrc = (int*)p;   p += (size_t)NE * 4;
    float* cw   = (float*)p; p += (size_t)NE * 4;
    unsigned* MXE1 = (unsigned*)p; p += 256 * 4;
    unsigned* MXE2 = (unsigned*)p; p += 512 * 4;
    float* MX1  = (float*)p; p += 256 * 4;
    float* HW3  = (float*)p; p += 512 * 4;
    float* MX2  = (float*)p; p += 512 * 4;
    float* HW5  = (float*)p; p += 256 * 4;

    const int BS = 256;
    const int gE = (NE + BS - 1) / BS;
    const int gN = (NN + BS - 1) / BS;
    const int NPB = 128;
    const int gP = (NN + NPB - 1) / NPB;

    // ---- CSR build ----
    hipMemsetAsync(cnt, 0, (size_t)NN * 4, stream);
    hipMemsetAsync(cnt2, 0, (size_t)NN * 4, stream);
    hipMemsetAsync(MXE1, 0, 256 * 4, stream);
    hipMemsetAsync(MXE2, 0, 512 * 4, stream);
    hipLaunchKernelGGL(k_hist, dim3(gE), dim3(BS), 0, stream, dst, cnt);
    hipLaunchKernelGGL(k_scanA, dim3(NBL_SCAN), dim3(BS), 0, stream, cnt, rp, parts);
    hipLaunchKernelGGL(k_scanB, dim3(1), dim3(512), 0, stream, parts);
    hipLaunchKernelGGL(k_scanC, dim3(NBL_SCAN), dim3(BS), 0, stream, rp, parts);
    hipLaunchKernelGGL(k_fill, dim3(gE), dim3(BS), 0, stream, src, dst, ew, ids, rp, cnt2, csrc, cw);

    // ---- S matrix (gather) ----
    hipLaunchKernelGGL(k_gS, dim3(NN * 8 / BS), dim3(BS), 0, stream, rp, csrc, cw, S);

    // ---- layer 1: gather x (3 feats, padded 4) then dense W1 -> h1(A) ----
    hipLaunchKernelGGL(k_gX, dim3(NN * 4 / BS), dim3(BS), 0, stream, x, rp, csrc, cw, AX);
    hipLaunchKernelGGL(k_l1, dim3(NN * 32 / BS), dim3(BS), 0, stream, AX, W1, b1, A);

    // ---- layer 2: tmp2(B) = h1@W2; agg2(A) = gather; pool -> MX1 ----
    hipLaunchKernelGGL(k_mm32, dim3(NN * 32 / BS), dim3(BS), 0, stream, A, W2, B);
    hipLaunchKernelGGL(k_gather<5>, dim3(NN * 32 / BS), dim3(BS), 0, stream, B, rp, csrc, cw, A);
    hipLaunchKernelGGL((k_pool2<5, NPB>), dim3(gP), dim3(BS), 0, stream, A, ids, b2, g1, be1, m1, v1, MXE1);
    hipLaunchKernelGGL(k_dec<32>, dim3(1), dim3(512), 0, stream, MXE1, MX1);

    // ---- layer 3 (collapsed): HW3 = MX1@W3; h3(B) = relu(S@HW3 + b3) ----
    hipLaunchKernelGGL(k_hw3, dim3(1), dim3(512), 0, stream, MX1, W3, HW3);
    hipLaunchKernelGGL(k_l3, dim3(NN * 64 / BS), dim3(BS), 0, stream, S, HW3, b3, B);

    // ---- layer 4: tmp4(A) = h3@W4; agg4(B) = gather; pool -> MX2 ----
    hipLaunchKernelGGL(k_mm64, dim3(NN * 64 / BS), dim3(BS), 0, stream, B, W4, A);
    hipLaunchKernelGGL(k_gather<6>, dim3(NN * 64 / BS), dim3(BS), 0, stream, A, rp, csrc, cw, B);
    hipLaunchKernelGGL((k_pool2<6, NPB>), dim3(gP), dim3(BS), 0, stream, B, ids, b4, g2, be2, m2, v2, MXE2);
    hipLaunchKernelGGL(k_dec<64>, dim3(1), dim3(512), 0, stream, MXE2, MX2);

    // ---- layer 5 (collapsed): HW5 = MX2@W5; out = softmax(S@HW5 + b5) ----
    hipLaunchKernelGGL(k_hw5, dim3(1), dim3(BS), 0, stream, MX2, W5, HW5);
    hipLaunchKernelGGL(k_out, dim3(gN), dim3(BS), 0, stream, S, HW5, b5, out);
}

// Round 4
// 473.548 us; speedup vs baseline: 3.2776x; 1.4404x over previous
//
#include <hip/hip_runtime.h>

#define NN 80000
#define NE 1280000
#define NGR 8
#define BN_EPS 1e-3f
#define NBL_SCAN 313   // ceil(NN/256)

typedef unsigned short ushort;

// ---------------- order-preserving float <-> unsigned encoding ----------------
__device__ __forceinline__ unsigned enc_f(float f) {
    unsigned b = __float_as_uint(f);
    return (f >= 0.f) ? (b | 0x80000000u) : ~b;
}
__device__ __forceinline__ float dec_f(unsigned u) {
    return (u & 0x80000000u) ? __uint_as_float(u & 0x7FFFFFFFu) : __uint_as_float(~u);
}
// fp32 -> bf16 (round-to-nearest-even)
__device__ __forceinline__ ushort f2bf(float f) {
    unsigned u = __float_as_uint(f);
    unsigned r = u + 0x7FFFu + ((u >> 16) & 1u);
    return (ushort)(r >> 16);
}
// 8 bf16 (16B) fused-multiply-accumulate into fp32 acc[8]
__device__ __forceinline__ void fma8(float* acc, const ushort* p, float w) {
    uint4 q = *(const uint4*)p;
    acc[0] += w * __uint_as_float((q.x & 0xFFFFu) << 16);
    acc[1] += w * __uint_as_float(q.x & 0xFFFF0000u);
    acc[2] += w * __uint_as_float((q.y & 0xFFFFu) << 16);
    acc[3] += w * __uint_as_float(q.y & 0xFFFF0000u);
    acc[4] += w * __uint_as_float((q.z & 0xFFFFu) << 16);
    acc[5] += w * __uint_as_float(q.z & 0xFFFF0000u);
    acc[6] += w * __uint_as_float((q.w & 0xFFFFu) << 16);
    acc[7] += w * __uint_as_float(q.w & 0xFFFF0000u);
}

// ================= CSR build =================
__global__ __launch_bounds__(256) void k_hist(const int* __restrict__ dst,
                                              int* __restrict__ cnt) {
    int e = blockIdx.x * 256 + threadIdx.x;
    if (e >= NE) return;
    atomicAdd(&cnt[dst[e]], 1);
}

__global__ __launch_bounds__(256) void k_scanA(const int* __restrict__ cnt,
                                               int* __restrict__ rp,
                                               int* __restrict__ parts) {
    __shared__ int sm[256];
    int tid = threadIdx.x;
    int i = blockIdx.x * 256 + tid;
    int v = (i < NN) ? cnt[i] : 0;
    sm[tid] = v;
    __syncthreads();
    #pragma unroll
    for (int off = 1; off < 256; off <<= 1) {
        int t2 = (tid >= off) ? sm[tid - off] : 0;
        __syncthreads();
        sm[tid] += t2;
        __syncthreads();
    }
    if (i < NN) rp[i] = sm[tid] - v;
    if (tid == 255) parts[blockIdx.x] = sm[255];
}

__global__ __launch_bounds__(512) void k_scanB(int* __restrict__ parts) {
    __shared__ int sm[512];
    int tid = threadIdx.x;
    int v = (tid < NBL_SCAN) ? parts[tid] : 0;
    sm[tid] = v;
    __syncthreads();
    #pragma unroll
    for (int off = 1; off < 512; off <<= 1) {
        int t2 = (tid >= off) ? sm[tid - off] : 0;
        __syncthreads();
        sm[tid] += t2;
        __syncthreads();
    }
    if (tid < NBL_SCAN) parts[tid] = sm[tid] - v;
}

__global__ __launch_bounds__(256) void k_scanC(int* __restrict__ rp,
                                               const int* __restrict__ parts) {
    int i = blockIdx.x * 256 + threadIdx.x;
    if (i < NN) rp[i] += parts[blockIdx.x];
    if (i == 0) rp[NN] = NE;
}

// fill CSR: cE[pos] = { src | (graph_of_src<<24), bits(w) }; reuses cnt via atomicSub
__global__ __launch_bounds__(256) void k_fill(const int* __restrict__ src,
                                              const int* __restrict__ dst,
                                              const float* __restrict__ ew,
                                              const int* __restrict__ ids,
                                              const int* __restrict__ rp,
                                              int* __restrict__ cnt,
                                              int2* __restrict__ cE) {
    int e = blockIdx.x * 256 + threadIdx.x;
    if (e >= NE) return;
    int d = dst[e];
    int s = src[e];
    int old = atomicSub(&cnt[d], 1);
    int pos = rp[d] + old - 1;
    cE[pos] = make_int2(s | (ids[s] << 24), __float_as_int(ew[e]));
}

// ================= gathers =================
__global__ __launch_bounds__(256) void k_gS(const int* __restrict__ rp,
                                            const int2* __restrict__ cE,
                                            float* __restrict__ S) {
    int t = blockIdx.x * 256 + threadIdx.x;   // NN*8
    int n = t >> 3, g = t & 7;
    int e0 = rp[n], e1 = rp[n + 1];
    float acc = 0.f;
    for (int i = e0; i < e1; ++i) {
        int2 a = cE[i];
        acc += ((a.x >> 24) == g) ? __int_as_float(a.y) : 0.f;
    }
    S[t] = acc;
}

__global__ __launch_bounds__(256) void k_gX(const float* __restrict__ x,
                                            const int* __restrict__ rp,
                                            const int2* __restrict__ cE,
                                            float* __restrict__ aggX) {
    int t = blockIdx.x * 256 + threadIdx.x;   // NN*4
    int n = t >> 2, f = t & 3;
    int e0 = rp[n], e1 = rp[n + 1];
    float acc = 0.f;
    if (f < 3)
        for (int i = e0; i < e1; ++i) {
            int2 a = cE[i];
            acc += __int_as_float(a.y) * x[(a.x & 0xFFFFFF) * 3 + f];
        }
    aggX[t] = acc;
}

// ---- fused gather (bf16 rows) + bias + relu + BN + per-graph max pool ----
template <int LOGF>
__global__ __launch_bounds__(256) void k_gpool(const ushort* __restrict__ th,
                                               const int* __restrict__ rp,
                                               const int2* __restrict__ cE,
                                               const int* __restrict__ ids,
                                               const float* __restrict__ b,
                                               const float* __restrict__ g,
                                               const float* __restrict__ be,
                                               const float* __restrict__ m,
                                               const float* __restrict__ v,
                                               unsigned* __restrict__ mxe) {
    const int F = 1 << LOGF;
    const int CPN = F >> 3;         // lanes per node (16B chunks of 8 bf16)
    const int NPB = 256 / CPN;      // nodes per block
    __shared__ unsigned lmx[NGR * F];
    for (int i = threadIdx.x; i < NGR * F; i += 256) lmx[i] = 0u;
    __syncthreads();
    int c = threadIdx.x & (CPN - 1);
    int n = blockIdx.x * NPB + (threadIdx.x >> (LOGF - 3));
    if (n < NN) {
        int e0 = rp[n], e1 = rp[n + 1];
        float acc[8] = {0, 0, 0, 0, 0, 0, 0, 0};
        float acc2[8] = {0, 0, 0, 0, 0, 0, 0, 0};
        int i = e0;
        for (; i + 2 <= e1; i += 2) {
            int2 a0 = cE[i], a1 = cE[i + 1];
            const ushort* p0 = th + (((size_t)(a0.x & 0xFFFFFF)) << LOGF) + (c << 3);
            const ushort* p1 = th + (((size_t)(a1.x & 0xFFFFFF)) << LOGF) + (c << 3);
            fma8(acc, p0, __int_as_float(a0.y));
            fma8(acc2, p1, __int_as_float(a1.y));
        }
        if (i < e1) {
            int2 a0 = cE[i];
            fma8(acc, th + (((size_t)(a0.x & 0xFFFFFF)) << LOGF) + (c << 3),
                 __int_as_float(a0.y));
        }
        int gg = ids[n];
        #pragma unroll
        for (int j = 0; j < 8; ++j) {
            int f = (c << 3) + j;
            float scale = g[f] * rsqrtf(v[f] + BN_EPS);
            float h = fmaxf(acc[j] + acc2[j] + b[f], 0.f);
            float val = (h - m[f]) * scale + be[f];
            atomicMax(&lmx[gg * F + f], enc_f(val));
        }
    }
    __syncthreads();
    for (int i = threadIdx.x; i < NGR * F; i += 256) {
        unsigned u = lmx[i];
        if (u) atomicMax(&mxe[i], u);
    }
}

// ================= dense layers =================
__global__ __launch_bounds__(256) void k_l1(const float* __restrict__ aggX,
                                            const float* __restrict__ W1,
                                            const float* __restrict__ b1,
                                            float* __restrict__ h1) {
    int t = blockIdx.x * 256 + threadIdx.x;
    int n = t >> 5, f = t & 31;
    float acc = b1[f];
    #pragma unroll
    for (int k = 0; k < 3; ++k) acc += aggX[n * 4 + k] * W1[k * 32 + f];
    h1[t] = fmaxf(acc, 0.f);
}

// tmp2 = h1 @ W2 -> bf16
__global__ __launch_bounds__(256) void k_mm32b(const float* __restrict__ h,
                                               const float* __restrict__ W,
                                               ushort* __restrict__ o) {
    int t = blockIdx.x * 256 + threadIdx.x;
    int n = t >> 5, f = t & 31;
    float acc = 0.f;
    #pragma unroll
    for (int k = 0; k < 32; ++k) acc += h[n * 32 + k] * W[k * 32 + f];
    o[t] = f2bf(acc);
}

// tmp4 = h3 @ W4 -> bf16
__global__ __launch_bounds__(256) void k_mm64b(const float* __restrict__ h,
                                               const float* __restrict__ W,
                                               ushort* __restrict__ o) {
    int t = blockIdx.x * 256 + threadIdx.x;
    int n = t >> 6, f = t & 63;
    float acc = 0.f;
    #pragma unroll
    for (int k = 0; k < 64; ++k) acc += h[n * 64 + k] * W[k * 64 + f];
    o[t] = f2bf(acc);
}

// decode MXE1 (256) + HW3 = MX1@W3, one block 512
__global__ __launch_bounds__(512) void k_dechw3(const unsigned* __restrict__ mxe,
                                                const float* __restrict__ W,
                                                float* __restrict__ HW) {
    __shared__ float smx[256];
    int t = threadIdx.x;
    if (t < 256) smx[t] = mxe[t] ? dec_f(mxe[t]) : 0.f;
    __syncthreads();
    int g = t >> 6, f = t & 63;
    float acc = 0.f;
    #pragma unroll
    for (int k = 0; k < 32; ++k) acc += smx[g * 32 + k] * W[k * 64 + f];
    HW[t] = acc;
}

// decode MXE2 (512) + HW5 = MX2@W5, one block 512
__global__ __launch_bounds__(512) void k_dechw5(const unsigned* __restrict__ mxe,
                                                const float* __restrict__ W,
                                                float* __restrict__ HW) {
    __shared__ float smx[512];
    int t = threadIdx.x;
    smx[t] = mxe[t] ? dec_f(mxe[t]) : 0.f;
    __syncthreads();
    if (t >= 160) return;
    int g = t / 20, c = t % 20;
    float acc = 0.f;
    #pragma unroll
    for (int k = 0; k < 64; ++k) acc += smx[g * 64 + k] * W[k * 20 + c];
    HW[t] = acc;
}

__global__ __launch_bounds__(256) void k_l3(const float* __restrict__ S,
                                            const float* __restrict__ HW,
                                            const float* __restrict__ b,
                                            float* __restrict__ h3) {
    int t = blockIdx.x * 256 + threadIdx.x;
    int n = t >> 6, f = t & 63;
    float acc = b[f];
    #pragma unroll
    for (int g = 0; g < NGR; ++g) acc += S[n * NGR + g] * HW[g * 64 + f];
    h3[t] = fmaxf(acc, 0.f);
}

__global__ __launch_bounds__(256) void k_out(const float* __restrict__ S,
                                             const float* __restrict__ HW5,
                                             const float* __restrict__ b5,
                                             float* __restrict__ out) {
    __shared__ float hw[160];
    __shared__ float bb[20];
    int t = threadIdx.x;
    if (t < 160) hw[t] = HW5[t];
    if (t < 20) bb[t] = b5[t];
    __syncthreads();
    int n = blockIdx.x * 256 + t;
    if (n >= NN) return;
    const float4* sp = (const float4*)(S + n * 8);
    float4 s0 = sp[0], s1 = sp[1];
    float sv[8] = {s0.x, s0.y, s0.z, s0.w, s1.x, s1.y, s1.z, s1.w};
    float pre[20];
    #pragma unroll
    for (int c = 0; c < 20; ++c) {
        float acc = bb[c];
        #pragma unroll
        for (int g = 0; g < 8; ++g) acc += sv[g] * hw[g * 20 + c];
        pre[c] = acc;
    }
    float mx = pre[0];
    #pragma unroll
    for (int c = 1; c < 20; ++c) mx = fmaxf(mx, pre[c]);
    float sum = 0.f;
    #pragma unroll
    for (int c = 0; c < 20; ++c) { pre[c] = __expf(pre[c] - mx); sum += pre[c]; }
    float inv = 1.f / sum;
    #pragma unroll
    for (int c = 0; c < 20; ++c) out[n * 20 + c] = pre[c] * inv;
}

extern "C" void kernel_launch(void* const* d_in, const int* in_sizes, int n_in,
                              void* d_out, int out_size, void* d_ws, size_t ws_size,
                              hipStream_t stream) {
    const float* x   = (const float*)d_in[0];
    const float* ew  = (const float*)d_in[1];
    const int*   src = (const int*)d_in[2];
    const int*   dst = (const int*)d_in[3];
    const int*   ids = (const int*)d_in[4];
    const float* W1 = (const float*)d_in[5];  const float* b1 = (const float*)d_in[6];
    const float* W2 = (const float*)d_in[7];  const float* b2 = (const float*)d_in[8];
    const float* g1 = (const float*)d_in[9];  const float* be1 = (const float*)d_in[10];
    const float* m1 = (const float*)d_in[11]; const float* v1 = (const float*)d_in[12];
    const float* W3 = (const float*)d_in[13]; const float* b3 = (const float*)d_in[14];
    const float* W4 = (const float*)d_in[15]; const float* b4 = (const float*)d_in[16];
    const float* g2 = (const float*)d_in[17]; const float* be2 = (const float*)d_in[18];
    const float* m2 = (const float*)d_in[19]; const float* v2 = (const float*)d_in[20];
    const float* W5 = (const float*)d_in[21]; const float* b5 = (const float*)d_in[22];
    float* out = (float*)d_out;

    // workspace layout (~45 MB)
    char* p = (char*)d_ws;
    float*  S   = (float*)p;  p += (size_t)NN * 8 * 4;      // 2.56 MB
    float*  H   = (float*)p;  p += (size_t)NN * 64 * 4;     // h1 / h3 (fp32)
    ushort* T   = (ushort*)p; p += (size_t)NN * 64 * 2;     // tmp2 / tmp4 (bf16)
    float*  AX  = (float*)p;  p += (size_t)NN * 4 * 4;
    int*    rp  = (int*)p;    p += (size_t)(NN + 1) * 4;
    int*    cnt = (int*)p;    p += (size_t)NN * 4;
    int*    parts = (int*)p;  p += 512 * 4;
    int2*   cE  = (int2*)p;   p += (size_t)NE * 8;          // 10.24 MB
    unsigned* MXE1 = (unsigned*)p; p += 256 * 4;
    unsigned* MXE2 = (unsigned*)p; p += 512 * 4;
    float*  HW3 = (float*)p;  p += 512 * 4;
    float*  HW5 = (float*)p;  p += 256 * 4;

    const int BS = 256;
    const int gE = (NE + BS - 1) / BS;
    const int gN = (NN + BS - 1) / BS;

    // ---- CSR build ----
    hipMemsetAsync(cnt, 0, (size_t)NN * 4, stream);
    hipMemsetAsync(MXE1, 0, 256 * 4, stream);
    hipMemsetAsync(MXE2, 0, 512 * 4, stream);
    hipLaunchKernelGGL(k_hist, dim3(gE), dim3(BS), 0, stream, dst, cnt);
    hipLaunchKernelGGL(k_scanA, dim3(NBL_SCAN), dim3(BS), 0, stream, cnt, rp, parts);
    hipLaunchKernelGGL(k_scanB, dim3(1), dim3(512), 0, stream, parts);
    hipLaunchKernelGGL(k_scanC, dim3(NBL_SCAN), dim3(BS), 0, stream, rp, parts);
    hipLaunchKernelGGL(k_fill, dim3(gE), dim3(BS), 0, stream, src, dst, ew, ids, rp, cnt, cE);

    // ---- S matrix ----
    hipLaunchKernelGGL(k_gS, dim3(NN * 8 / BS), dim3(BS), 0, stream, rp, cE, S);

    // ---- layer 1 ----
    hipLaunchKernelGGL(k_gX, dim3(NN * 4 / BS), dim3(BS), 0, stream, x, rp, cE, AX);
    hipLaunchKernelGGL(k_l1, dim3(NN * 32 / BS), dim3(BS), 0, stream, AX, W1, b1, H);

    // ---- layer 2: tmp2(T,bf16) = h1@W2; fused gather+BN+pool -> MXE1 ----
    hipLaunchKernelGGL(k_mm32b, dim3(NN * 32 / BS), dim3(BS), 0, stream, H, W2, T);
    hipLaunchKernelGGL(k_gpool<5>, dim3(NN / 64), dim3(BS), 0, stream, T, rp, cE, ids, b2, g1, be1, m1, v1, MXE1);

    // ---- layer 3 (collapsed): HW3 = dec(MXE1)@W3; h3(H) = relu(S@HW3+b3) ----
    hipLaunchKernelGGL(k_dechw3, dim3(1), dim3(512), 0, stream, MXE1, W3, HW3);
    hipLaunchKernelGGL(k_l3, dim3(NN * 64 / BS), dim3(BS), 0, stream, S, HW3, b3, H);

    // ---- layer 4: tmp4(T,bf16) = h3@W4; fused gather+BN+pool -> MXE2 ----
    hipLaunchKernelGGL(k_mm64b, dim3(NN * 64 / BS), dim3(BS), 0, stream, H, W4, T);
    hipLaunchKernelGGL(k_gpool<6>, dim3(NN / 32), dim3(BS), 0, stream, T, rp, cE, ids, b4, g2, be2, m2, v2, MXE2);

    // ---- layer 5 (collapsed): HW5 = dec(MXE2)@W5; out = softmax(S@HW5+b5) ----
    hipLaunchKernelGGL(k_dechw5, dim3(1), dim3(512), 0, stream, MXE2, W5, HW5);
    hipLaunchKernelGGL(k_out, dim3(gN), dim3(BS), 0, stream, S, HW5, b5, out);
}

// Round 5
// 415.189 us; speedup vs baseline: 3.7383x; 1.1406x over previous
//
#include <hip/hip_runtime.h>

#define NN 80000
#define NE 1280000
#define NGR 8
#define BN_EPS 1e-3f
#define NBL_SCAN 313   // ceil(NN/256)

typedef unsigned short ushort;

// ---------------- order-preserving float <-> unsigned encoding ----------------
__device__ __forceinline__ unsigned enc_f(float f) {
    unsigned b = __float_as_uint(f);
    return (f >= 0.f) ? (b | 0x80000000u) : ~b;
}
__device__ __forceinline__ float dec_f(unsigned u) {
    return (u & 0x80000000u) ? __uint_as_float(u & 0x7FFFFFFFu) : __uint_as_float(~u);
}
// fp32 -> bf16 (round-to-nearest-even)
__device__ __forceinline__ ushort f2bf(float f) {
    unsigned u = __float_as_uint(f);
    unsigned r = u + 0x7FFFu + ((u >> 16) & 1u);
    return (ushort)(r >> 16);
}
// 8 bf16 (16B) fused-multiply-accumulate into fp32 acc[8]
__device__ __forceinline__ void fma8(float* acc, const ushort* p, float w) {
    uint4 q = *(const uint4*)p;
    acc[0] += w * __uint_as_float((q.x & 0xFFFFu) << 16);
    acc[1] += w * __uint_as_float(q.x & 0xFFFF0000u);
    acc[2] += w * __uint_as_float((q.y & 0xFFFFu) << 16);
    acc[3] += w * __uint_as_float(q.y & 0xFFFF0000u);
    acc[4] += w * __uint_as_float((q.z & 0xFFFFu) << 16);
    acc[5] += w * __uint_as_float(q.z & 0xFFFF0000u);
    acc[6] += w * __uint_as_float((q.w & 0xFFFFu) << 16);
    acc[7] += w * __uint_as_float(q.w & 0xFFFF0000u);
}

// ================= CSR build =================
__global__ __launch_bounds__(256) void k_hist(const int* __restrict__ dst,
                                              int* __restrict__ cnt) {
    int e = blockIdx.x * 256 + threadIdx.x;
    if (e >= NE) return;
    atomicAdd(&cnt[dst[e]], 1);
}

__global__ __launch_bounds__(256) void k_scanA(const int* __restrict__ cnt,
                                               int* __restrict__ rp,
                                               int* __restrict__ parts) {
    __shared__ int sm[256];
    int tid = threadIdx.x;
    int i = blockIdx.x * 256 + tid;
    int v = (i < NN) ? cnt[i] : 0;
    sm[tid] = v;
    __syncthreads();
    #pragma unroll
    for (int off = 1; off < 256; off <<= 1) {
        int t2 = (tid >= off) ? sm[tid - off] : 0;
        __syncthreads();
        sm[tid] += t2;
        __syncthreads();
    }
    if (i < NN) rp[i] = sm[tid] - v;
    if (tid == 255) parts[blockIdx.x] = sm[255];
}

__global__ __launch_bounds__(512) void k_scanB(int* __restrict__ parts) {
    __shared__ int sm[512];
    int tid = threadIdx.x;
    int v = (tid < NBL_SCAN) ? parts[tid] : 0;
    sm[tid] = v;
    __syncthreads();
    #pragma unroll
    for (int off = 1; off < 512; off <<= 1) {
        int t2 = (tid >= off) ? sm[tid - off] : 0;
        __syncthreads();
        sm[tid] += t2;
        __syncthreads();
    }
    if (tid < NBL_SCAN) parts[tid] = sm[tid] - v;
}

__global__ __launch_bounds__(256) void k_scanC(int* __restrict__ rp,
                                               const int* __restrict__ parts) {
    int i = blockIdx.x * 256 + threadIdx.x;
    if (i < NN) rp[i] += parts[blockIdx.x];
    if (i == 0) rp[NN] = NE;
}

// fill CSR, dst-range pass [d0,d1): writes confined to a 2.56MB L2-resident slice
__global__ __launch_bounds__(256) void k_fill(const int* __restrict__ src,
                                              const int* __restrict__ dst,
                                              const float* __restrict__ ew,
                                              const int* __restrict__ ids,
                                              const int* __restrict__ rp,
                                              int* __restrict__ cnt,
                                              int2* __restrict__ cE,
                                              int d0, int d1) {
    int e = blockIdx.x * 256 + threadIdx.x;
    if (e >= NE) return;
    int d = dst[e];
    if (d < d0 || d >= d1) return;
    int s = src[e];
    int old = atomicSub(&cnt[d], 1);
    cE[rp[d] + old - 1] = make_int2(s | (ids[s] << 24), __float_as_int(ew[e]));
}

// ================= fused S + aggX gather (one thread per node) =================
__global__ __launch_bounds__(256) void k_gSX(const float* __restrict__ x,
                                             const int* __restrict__ rp,
                                             const int2* __restrict__ cE,
                                             float* __restrict__ S,
                                             float* __restrict__ AX) {
    int n = blockIdx.x * 256 + threadIdx.x;
    if (n >= NN) return;
    int e0 = rp[n], e1 = rp[n + 1];
    float sv[8] = {0, 0, 0, 0, 0, 0, 0, 0};
    float ax0 = 0.f, ax1 = 0.f, ax2 = 0.f;
    for (int i = e0; i < e1; ++i) {
        int2 a = cE[i];
        float w = __int_as_float(a.y);
        int s = a.x & 0xFFFFFF;
        int gg = a.x >> 24;
        #pragma unroll
        for (int g = 0; g < 8; ++g) sv[g] += (gg == g) ? w : 0.f;
        const float* xp = x + s * 3;
        ax0 += w * xp[0]; ax1 += w * xp[1]; ax2 += w * xp[2];
    }
    float4* Sp = (float4*)(S + n * 8);
    Sp[0] = make_float4(sv[0], sv[1], sv[2], sv[3]);
    Sp[1] = make_float4(sv[4], sv[5], sv[6], sv[7]);
    *(float4*)(AX + n * 4) = make_float4(ax0, ax1, ax2, 0.f);
}

// ======== fused layer1+layer2-matmul: tmp2 = (relu(AX@W1+b1))@W2 -> bf16 ========
__global__ __launch_bounds__(256) void k_l12(const float* __restrict__ AX,
                                             const float* __restrict__ W1,
                                             const float* __restrict__ b1,
                                             const float* __restrict__ W2,
                                             ushort* __restrict__ T) {
    __shared__ float h1s[256];           // 8 nodes x 32
    int t = threadIdx.x;
    int r = t >> 5, f = t & 31;
    int n = blockIdx.x * 8 + r;
    const float* ax = AX + n * 4;
    float acc = b1[f] + ax[0] * W1[f] + ax[1] * W1[32 + f] + ax[2] * W1[64 + f];
    h1s[t] = fmaxf(acc, 0.f);
    __syncthreads();
    float o = 0.f;
    #pragma unroll
    for (int k = 0; k < 32; ++k) o += h1s[r * 32 + k] * W2[k * 32 + f];
    T[n * 32 + f] = f2bf(o);
}

// ======== fused layer3+layer4-matmul: tmp4 = (relu(S@HW3+b3))@W4 -> bf16 ========
__global__ __launch_bounds__(256) void k_l34(const float* __restrict__ S,
                                             const float* __restrict__ HW3,
                                             const float* __restrict__ b3,
                                             const float* __restrict__ W4,
                                             ushort* __restrict__ T) {
    __shared__ float h3s[256];           // 4 nodes x 64
    int t = threadIdx.x;
    int r = t >> 6, f = t & 63;
    int n = blockIdx.x * 4 + r;
    const float* sp = S + n * 8;
    float acc = b3[f];
    #pragma unroll
    for (int g = 0; g < 8; ++g) acc += sp[g] * HW3[g * 64 + f];
    h3s[t] = fmaxf(acc, 0.f);
    __syncthreads();
    float o = 0.f;
    #pragma unroll
    for (int k = 0; k < 64; ++k) o += h3s[r * 64 + k] * W4[k * 64 + f];
    T[n * 64 + f] = f2bf(o);
}

// ---- fused gather (bf16 rows) + bias + relu + BN + per-graph max pool ----
template <int LOGF>
__global__ __launch_bounds__(256) void k_gpool(const ushort* __restrict__ th,
                                               const int* __restrict__ rp,
                                               const int2* __restrict__ cE,
                                               const int* __restrict__ ids,
                                               const float* __restrict__ b,
                                               const float* __restrict__ g,
                                               const float* __restrict__ be,
                                               const float* __restrict__ m,
                                               const float* __restrict__ v,
                                               unsigned* __restrict__ mxe) {
    const int F = 1 << LOGF;
    const int CPN = F >> 3;
    const int NPB = 256 / CPN;
    __shared__ unsigned lmx[NGR * F];
    for (int i = threadIdx.x; i < NGR * F; i += 256) lmx[i] = 0u;
    __syncthreads();
    int c = threadIdx.x & (CPN - 1);
    int n = blockIdx.x * NPB + (threadIdx.x >> (LOGF - 3));
    if (n < NN) {
        int e0 = rp[n], e1 = rp[n + 1];
        float acc[8] = {0, 0, 0, 0, 0, 0, 0, 0};
        float acc2[8] = {0, 0, 0, 0, 0, 0, 0, 0};
        int i = e0;
        for (; i + 2 <= e1; i += 2) {
            int2 a0 = cE[i], a1 = cE[i + 1];
            const ushort* p0 = th + (((size_t)(a0.x & 0xFFFFFF)) << LOGF) + (c << 3);
            const ushort* p1 = th + (((size_t)(a1.x & 0xFFFFFF)) << LOGF) + (c << 3);
            fma8(acc, p0, __int_as_float(a0.y));
            fma8(acc2, p1, __int_as_float(a1.y));
        }
        if (i < e1) {
            int2 a0 = cE[i];
            fma8(acc, th + (((size_t)(a0.x & 0xFFFFFF)) << LOGF) + (c << 3),
                 __int_as_float(a0.y));
        }
        int gg = ids[n];
        #pragma unroll
        for (int j = 0; j < 8; ++j) {
            int f = (c << 3) + j;
            float scale = g[f] * rsqrtf(v[f] + BN_EPS);
            float h = fmaxf(acc[j] + acc2[j] + b[f], 0.f);
            float val = (h - m[f]) * scale + be[f];
            atomicMax(&lmx[gg * F + f], enc_f(val));
        }
    }
    __syncthreads();
    for (int i = threadIdx.x; i < NGR * F; i += 256) {
        unsigned u = lmx[i];
        if (u) atomicMax(&mxe[i], u);
    }
}

// decode MXE1 (256) + HW3 = MX1@W3, one block 512
__global__ __launch_bounds__(512) void k_dechw3(const unsigned* __restrict__ mxe,
                                                const float* __restrict__ W,
                                                float* __restrict__ HW) {
    __shared__ float smx[256];
    int t = threadIdx.x;
    if (t < 256) smx[t] = mxe[t] ? dec_f(mxe[t]) : 0.f;
    __syncthreads();
    int g = t >> 6, f = t & 63;
    float acc = 0.f;
    #pragma unroll
    for (int k = 0; k < 32; ++k) acc += smx[g * 32 + k] * W[k * 64 + f];
    HW[t] = acc;
}

// decode MXE2 (512) + HW5 = MX2@W5, one block 512
__global__ __launch_bounds__(512) void k_dechw5(const unsigned* __restrict__ mxe,
                                                const float* __restrict__ W,
                                                float* __restrict__ HW) {
    __shared__ float smx[512];
    int t = threadIdx.x;
    smx[t] = mxe[t] ? dec_f(mxe[t]) : 0.f;
    __syncthreads();
    if (t >= 160) return;
    int g = t / 20, c = t % 20;
    float acc = 0.f;
    #pragma unroll
    for (int k = 0; k < 64; ++k) acc += smx[g * 64 + k] * W[k * 20 + c];
    HW[t] = acc;
}

__global__ __launch_bounds__(256) void k_out(const float* __restrict__ S,
                                             const float* __restrict__ HW5,
                                             const float* __restrict__ b5,
                                             float* __restrict__ out) {
    __shared__ float hw[160];
    __shared__ float bb[20];
    int t = threadIdx.x;
    if (t < 160) hw[t] = HW5[t];
    if (t < 20) bb[t] = b5[t];
    __syncthreads();
    int n = blockIdx.x * 256 + t;
    if (n >= NN) return;
    const float4* sp = (const float4*)(S + n * 8);
    float4 s0 = sp[0], s1 = sp[1];
    float sv[8] = {s0.x, s0.y, s0.z, s0.w, s1.x, s1.y, s1.z, s1.w};
    float pre[20];
    #pragma unroll
    for (int c = 0; c < 20; ++c) {
        float acc = bb[c];
        #pragma unroll
        for (int g = 0; g < 8; ++g) acc += sv[g] * hw[g * 20 + c];
        pre[c] = acc;
    }
    float mx = pre[0];
    #pragma unroll
    for (int c = 1; c < 20; ++c) mx = fmaxf(mx, pre[c]);
    float sum = 0.f;
    #pragma unroll
    for (int c = 0; c < 20; ++c) { pre[c] = __expf(pre[c] - mx); sum += pre[c]; }
    float inv = 1.f / sum;
    #pragma unroll
    for (int c = 0; c < 20; ++c) out[n * 20 + c] = pre[c] * inv;
}

extern "C" void kernel_launch(void* const* d_in, const int* in_sizes, int n_in,
                              void* d_out, int out_size, void* d_ws, size_t ws_size,
                              hipStream_t stream) {
    const float* x   = (const float*)d_in[0];
    const float* ew  = (const float*)d_in[1];
    const int*   src = (const int*)d_in[2];
    const int*   dst = (const int*)d_in[3];
    const int*   ids = (const int*)d_in[4];
    const float* W1 = (const float*)d_in[5];  const float* b1 = (const float*)d_in[6];
    const float* W2 = (const float*)d_in[7];  const float* b2 = (const float*)d_in[8];
    const float* g1 = (const float*)d_in[9];  const float* be1 = (const float*)d_in[10];
    const float* m1 = (const float*)d_in[11]; const float* v1 = (const float*)d_in[12];
    const float* W3 = (const float*)d_in[13]; const float* b3 = (const float*)d_in[14];
    const float* W4 = (const float*)d_in[15]; const float* b4 = (const float*)d_in[16];
    const float* g2 = (const float*)d_in[17]; const float* be2 = (const float*)d_in[18];
    const float* m2 = (const float*)d_in[19]; const float* v2 = (const float*)d_in[20];
    const float* W5 = (const float*)d_in[21]; const float* b5 = (const float*)d_in[22];
    float* out = (float*)d_out;

    // workspace layout (~25 MB)
    char* p = (char*)d_ws;
    float*  S   = (float*)p;  p += (size_t)NN * 8 * 4;      // 2.56 MB
    ushort* T   = (ushort*)p; p += (size_t)NN * 64 * 2;     // tmp2 / tmp4 (bf16)
    float*  AX  = (float*)p;  p += (size_t)NN * 4 * 4;
    int*    rp  = (int*)p;    p += (size_t)(NN + 1) * 4;
    int*    cnt = (int*)p;    p += (size_t)NN * 4;
    int*    parts = (int*)p;  p += 512 * 4;
    int2*   cE  = (int2*)p;   p += (size_t)NE * 8;          // 10.24 MB
    unsigned* MXE1 = (unsigned*)p; p += 256 * 4;
    unsigned* MXE2 = (unsigned*)p; p += 512 * 4;            // contiguous w/ MXE1
    float*  HW3 = (float*)p;  p += 512 * 4;
    float*  HW5 = (float*)p;  p += 256 * 4;

    const int BS = 256;
    const int gE = (NE + BS - 1) / BS;
    const int gN = (NN + BS - 1) / BS;

    // ---- CSR build ----
    hipMemsetAsync(cnt, 0, (size_t)NN * 4, stream);
    hipMemsetAsync(MXE1, 0, 768 * 4, stream);   // MXE1+MXE2 in one shot
    hipLaunchKernelGGL(k_hist, dim3(gE), dim3(BS), 0, stream, dst, cnt);
    hipLaunchKernelGGL(k_scanA, dim3(NBL_SCAN), dim3(BS), 0, stream, cnt, rp, parts);
    hipLaunchKernelGGL(k_scanB, dim3(1), dim3(512), 0, stream, parts);
    hipLaunchKernelGGL(k_scanC, dim3(NBL_SCAN), dim3(BS), 0, stream, rp, parts);
    // 4 sequential dst-range passes: each pass's writes fit in a per-XCD L2 slice
    for (int pass = 0; pass < 4; ++pass)
        hipLaunchKernelGGL(k_fill, dim3(gE), dim3(BS), 0, stream, src, dst, ew, ids,
                           rp, cnt, cE, pass * 20000, (pass + 1) * 20000);

    // ---- fused S + aggX gather ----
    hipLaunchKernelGGL(k_gSX, dim3(gN), dim3(BS), 0, stream, x, rp, cE, S, AX);

    // ---- layers 1+2 dense fused: tmp2(T) = relu(AX@W1+b1)@W2 ----
    hipLaunchKernelGGL(k_l12, dim3(NN / 8), dim3(BS), 0, stream, AX, W1, b1, W2, T);
    hipLaunchKernelGGL(k_gpool<5>, dim3(NN / 64), dim3(BS), 0, stream, T, rp, cE, ids, b2, g1, be1, m1, v1, MXE1);

    // ---- layers 3+4: HW3 = dec(MXE1)@W3; tmp4(T) = relu(S@HW3+b3)@W4 ----
    hipLaunchKernelGGL(k_dechw3, dim3(1), dim3(512), 0, stream, MXE1, W3, HW3);
    hipLaunchKernelGGL(k_l34, dim3(NN / 4), dim3(BS), 0, stream, S, HW3, b3, W4, T);
    hipLaunchKernelGGL(k_gpool<6>, dim3(NN / 32), dim3(BS), 0, stream, T, rp, cE, ids, b4, g2, be2, m2, v2, MXE2);

    // ---- layer 5 (collapsed): HW5 = dec(MXE2)@W5; out = softmax(S@HW5+b5) ----
    hipLaunchKernelGGL(k_dechw5, dim3(1), dim3(512), 0, stream, MXE2, W5, HW5);
    hipLaunchKernelGGL(k_out, dim3(gN), dim3(BS), 0, stream, S, HW5, b5, out);
}

// Round 6
// 317.032 us; speedup vs baseline: 4.8958x; 1.3096x over previous
//
#include <hip/hip_runtime.h>

#define NN 80000
#define NE 1280000
#define NGR 8
#define BN_EPS 1e-3f
#define NB 313      // ceil(NN/256) coarse dst-buckets
#define GB 320      // blocks for bhist/bfill
#define CHK 4000    // edges per block (GB*CHK == NE)

typedef unsigned short ushort;

// ---------------- order-preserving float <-> unsigned encoding ----------------
__device__ __forceinline__ unsigned enc_f(float f) {
    unsigned b = __float_as_uint(f);
    return (f >= 0.f) ? (b | 0x80000000u) : ~b;
}
__device__ __forceinline__ float dec_f(unsigned u) {
    return (u & 0x80000000u) ? __uint_as_float(u & 0x7FFFFFFFu) : __uint_as_float(~u);
}
// fp32 -> bf16 (round-to-nearest-even)
__device__ __forceinline__ ushort f2bf(float f) {
    unsigned u = __float_as_uint(f);
    unsigned r = u + 0x7FFFu + ((u >> 16) & 1u);
    return (ushort)(r >> 16);
}
// 8 bf16 (16B) fused-multiply-accumulate into fp32 acc[8]
__device__ __forceinline__ void fma8(float* acc, const ushort* p, float w) {
    uint4 q = *(const uint4*)p;
    acc[0] += w * __uint_as_float((q.x & 0xFFFFu) << 16);
    acc[1] += w * __uint_as_float(q.x & 0xFFFF0000u);
    acc[2] += w * __uint_as_float((q.y & 0xFFFFu) << 16);
    acc[3] += w * __uint_as_float(q.y & 0xFFFF0000u);
    acc[4] += w * __uint_as_float((q.z & 0xFFFFu) << 16);
    acc[5] += w * __uint_as_float(q.z & 0xFFFF0000u);
    acc[6] += w * __uint_as_float((q.w & 0xFFFFu) << 16);
    acc[7] += w * __uint_as_float(q.w & 0xFFFF0000u);
}

// ================= CSR build: 2-level counting sort =================
// Pass A: coarse histogram (dst>>8), LDS-privatized, ~100k global atomics
__global__ __launch_bounds__(256) void k_bhist(const int* __restrict__ dst,
                                               int* __restrict__ bcnt) {
    __shared__ int lh[NB];
    for (int i = threadIdx.x; i < NB; i += 256) lh[i] = 0;
    __syncthreads();
    int e0 = blockIdx.x * CHK;
    for (int e = e0 + threadIdx.x; e < e0 + CHK; e += 256)
        atomicAdd(&lh[dst[e] >> 8], 1);
    __syncthreads();
    for (int i = threadIdx.x; i < NB; i += 256) {
        int c = lh[i];
        if (c) atomicAdd(&bcnt[i], c);
    }
}

// Pass B: exclusive scan of NB bucket counts -> bo; init cursors
__global__ __launch_bounds__(512) void k_bscan(const int* __restrict__ bcnt,
                                               int* __restrict__ bo,
                                               int* __restrict__ bcur) {
    __shared__ int sm[512];
    int tid = threadIdx.x;
    int v = (tid < NB) ? bcnt[tid] : 0;
    sm[tid] = v;
    __syncthreads();
    #pragma unroll
    for (int off = 1; off < 512; off <<= 1) {
        int t2 = (tid >= off) ? sm[tid - off] : 0;
        __syncthreads();
        sm[tid] += t2;
        __syncthreads();
    }
    if (tid < NB) {
        int ex = sm[tid] - v;
        bo[tid] = ex;
        bcur[tid] = ex;
    }
    if (tid == 0) bo[NB] = NE;
}

// Pass C: bucket the edges. Per block: LDS count, one claim-atomic per bucket,
// then contiguous chunk writes. Payload packs src(17b) | g(3b,@17) | dlow(8b,@20).
__global__ __launch_bounds__(256) void k_bfill(const int* __restrict__ src,
                                               const int* __restrict__ dst,
                                               const float* __restrict__ ew,
                                               const int* __restrict__ ids,
                                               int* __restrict__ bcur,
                                               int2* __restrict__ cB) {
    __shared__ int lh[NB];
    __shared__ int lbase[NB];
    for (int i = threadIdx.x; i < NB; i += 256) lh[i] = 0;
    __syncthreads();
    int e0 = blockIdx.x * CHK;
    for (int e = e0 + threadIdx.x; e < e0 + CHK; e += 256)
        atomicAdd(&lh[dst[e] >> 8], 1);
    __syncthreads();
    for (int i = threadIdx.x; i < NB; i += 256) {
        int c = lh[i];
        lbase[i] = c ? atomicAdd(&bcur[i], c) : 0;
        lh[i] = 0;
    }
    __syncthreads();
    for (int e = e0 + threadIdx.x; e < e0 + CHK; e += 256) {
        int d = dst[e];
        int b = d >> 8;
        int s = src[e];
        int pos = lbase[b] + atomicAdd(&lh[b], 1);
        cB[pos] = make_int2(s | (ids[s] << 17) | ((d & 255) << 20),
                            __float_as_int(ew[e]));
    }
}

// Pass D: one block per bucket. LDS 256-bin counting sort by dlow; emits rp and
// final cE (src | g<<24, w) sorted by dst. Zero global atomics.
__global__ __launch_bounds__(256) void k_insort(const int* __restrict__ bo,
                                                const int2* __restrict__ cB,
                                                int* __restrict__ rp,
                                                int2* __restrict__ cE) {
    __shared__ int lc[256];
    __shared__ int loff[256];
    __shared__ int sm[256];
    int b = blockIdx.x, tid = threadIdx.x;
    int s0 = bo[b], s1 = bo[b + 1];
    lc[tid] = 0;
    __syncthreads();
    for (int i = s0 + tid; i < s1; i += 256)
        atomicAdd(&lc[(cB[i].x >> 20) & 255], 1);
    __syncthreads();
    int v = lc[tid];
    sm[tid] = v;
    __syncthreads();
    #pragma unroll
    for (int off = 1; off < 256; off <<= 1) {
        int t2 = (tid >= off) ? sm[tid - off] : 0;
        __syncthreads();
        sm[tid] += t2;
        __syncthreads();
    }
    loff[tid] = sm[tid] - v;   // exclusive within bucket
    int n = b * 256 + tid;
    if (n < NN) rp[n] = s0 + loff[tid];
    if (b == NB - 1 && tid == 0) rp[NN] = NE;
    lc[tid] = 0;
    __syncthreads();
    for (int i = s0 + tid; i < s1; i += 256) {
        int2 a = cB[i];
        int dlow = (a.x >> 20) & 255;
        int pos = s0 + loff[dlow] + atomicAdd(&lc[dlow], 1);
        cE[pos] = make_int2((a.x & 0x1FFFF) | (((a.x >> 17) & 7) << 24), a.y);
    }
}

// ================= fused S + aggX gather (one thread per node) =================
__global__ __launch_bounds__(256) void k_gSX(const float* __restrict__ x,
                                             const int* __restrict__ rp,
                                             const int2* __restrict__ cE,
                                             float* __restrict__ S,
                                             float* __restrict__ AX) {
    int n = blockIdx.x * 256 + threadIdx.x;
    if (n >= NN) return;
    int e0 = rp[n], e1 = rp[n + 1];
    float sv[8] = {0, 0, 0, 0, 0, 0, 0, 0};
    float ax0 = 0.f, ax1 = 0.f, ax2 = 0.f;
    for (int i = e0; i < e1; ++i) {
        int2 a = cE[i];
        float w = __int_as_float(a.y);
        int s = a.x & 0xFFFFFF;
        int gg = a.x >> 24;
        #pragma unroll
        for (int g = 0; g < 8; ++g) sv[g] += (gg == g) ? w : 0.f;
        const float* xp = x + s * 3;
        ax0 += w * xp[0]; ax1 += w * xp[1]; ax2 += w * xp[2];
    }
    float4* Sp = (float4*)(S + n * 8);
    Sp[0] = make_float4(sv[0], sv[1], sv[2], sv[3]);
    Sp[1] = make_float4(sv[4], sv[5], sv[6], sv[7]);
    *(float4*)(AX + n * 4) = make_float4(ax0, ax1, ax2, 0.f);
}

// ======== fused layer1+layer2-matmul: tmp2 = (relu(AX@W1+b1))@W2 -> bf16 ========
__global__ __launch_bounds__(256) void k_l12(const float* __restrict__ AX,
                                             const float* __restrict__ W1,
                                             const float* __restrict__ b1,
                                             const float* __restrict__ W2,
                                             ushort* __restrict__ T) {
    __shared__ float h1s[256];           // 8 nodes x 32
    int t = threadIdx.x;
    int r = t >> 5, f = t & 31;
    int n = blockIdx.x * 8 + r;
    const float* ax = AX + n * 4;
    float acc = b1[f] + ax[0] * W1[f] + ax[1] * W1[32 + f] + ax[2] * W1[64 + f];
    h1s[t] = fmaxf(acc, 0.f);
    __syncthreads();
    float o = 0.f;
    #pragma unroll
    for (int k = 0; k < 32; ++k) o += h1s[r * 32 + k] * W2[k * 32 + f];
    T[n * 32 + f] = f2bf(o);
}

// ======== fused layer3+layer4-matmul: tmp4 = (relu(S@HW3+b3))@W4 -> bf16 ========
__global__ __launch_bounds__(256) void k_l34(const float* __restrict__ S,
                                             const float* __restrict__ HW3,
                                             const float* __restrict__ b3,
                                             const float* __restrict__ W4,
                                             ushort* __restrict__ T) {
    __shared__ float h3s[256];           // 4 nodes x 64
    int t = threadIdx.x;
    int r = t >> 6, f = t & 63;
    int n = blockIdx.x * 4 + r;
    const float* sp = S + n * 8;
    float acc = b3[f];
    #pragma unroll
    for (int g = 0; g < 8; ++g) acc += sp[g] * HW3[g * 64 + f];
    h3s[t] = fmaxf(acc, 0.f);
    __syncthreads();
    float o = 0.f;
    #pragma unroll
    for (int k = 0; k < 64; ++k) o += h3s[r * 64 + k] * W4[k * 64 + f];
    T[n * 64 + f] = f2bf(o);
}

// ---- fused gather (bf16 rows) + bias + relu + BN + per-graph max pool ----
template <int LOGF>
__global__ __launch_bounds__(256) void k_gpool(const ushort* __restrict__ th,
                                               const int* __restrict__ rp,
                                               const int2* __restrict__ cE,
                                               const int* __restrict__ ids,
                                               const float* __restrict__ b,
                                               const float* __restrict__ g,
                                               const float* __restrict__ be,
                                               const float* __restrict__ m,
                                               const float* __restrict__ v,
                                               unsigned* __restrict__ mxe) {
    const int F = 1 << LOGF;
    const int CPN = F >> 3;
    const int NPB = 256 / CPN;
    __shared__ unsigned lmx[NGR * F];
    for (int i = threadIdx.x; i < NGR * F; i += 256) lmx[i] = 0u;
    __syncthreads();
    int c = threadIdx.x & (CPN - 1);
    int n = blockIdx.x * NPB + (threadIdx.x >> (LOGF - 3));
    if (n < NN) {
        int e0 = rp[n], e1 = rp[n + 1];
        float acc[8] = {0, 0, 0, 0, 0, 0, 0, 0};
        float acc2[8] = {0, 0, 0, 0, 0, 0, 0, 0};
        int i = e0;
        for (; i + 2 <= e1; i += 2) {
            int2 a0 = cE[i], a1 = cE[i + 1];
            const ushort* p0 = th + (((size_t)(a0.x & 0xFFFFFF)) << LOGF) + (c << 3);
            const ushort* p1 = th + (((size_t)(a1.x & 0xFFFFFF)) << LOGF) + (c << 3);
            fma8(acc, p0, __int_as_float(a0.y));
            fma8(acc2, p1, __int_as_float(a1.y));
        }
        if (i < e1) {
            int2 a0 = cE[i];
            fma8(acc, th + (((size_t)(a0.x & 0xFFFFFF)) << LOGF) + (c << 3),
                 __int_as_float(a0.y));
        }
        int gg = ids[n];
        #pragma unroll
        for (int j = 0; j < 8; ++j) {
            int f = (c << 3) + j;
            float scale = g[f] * rsqrtf(v[f] + BN_EPS);
            float h = fmaxf(acc[j] + acc2[j] + b[f], 0.f);
            float val = (h - m[f]) * scale + be[f];
            atomicMax(&lmx[gg * F + f], enc_f(val));
        }
    }
    __syncthreads();
    for (int i = threadIdx.x; i < NGR * F; i += 256) {
        unsigned u = lmx[i];
        if (u) atomicMax(&mxe[i], u);
    }
}

// decode MXE1 (256) + HW3 = MX1@W3, one block 512
__global__ __launch_bounds__(512) void k_dechw3(const unsigned* __restrict__ mxe,
                                                const float* __restrict__ W,
                                                float* __restrict__ HW) {
    __shared__ float smx[256];
    int t = threadIdx.x;
    if (t < 256) smx[t] = mxe[t] ? dec_f(mxe[t]) : 0.f;
    __syncthreads();
    int g = t >> 6, f = t & 63;
    float acc = 0.f;
    #pragma unroll
    for (int k = 0; k < 32; ++k) acc += smx[g * 32 + k] * W[k * 64 + f];
    HW[t] = acc;
}

// decode MXE2 (512) + HW5 = MX2@W5, one block 512
__global__ __launch_bounds__(512) void k_dechw5(const unsigned* __restrict__ mxe,
                                                const float* __restrict__ W,
                                                float* __restrict__ HW) {
    __shared__ float smx[512];
    int t = threadIdx.x;
    smx[t] = mxe[t] ? dec_f(mxe[t]) : 0.f;
    __syncthreads();
    if (t >= 160) return;
    int g = t / 20, c = t % 20;
    float acc = 0.f;
    #pragma unroll
    for (int k = 0; k < 64; ++k) acc += smx[g * 64 + k] * W[k * 20 + c];
    HW[t] = acc;
}

__global__ __launch_bounds__(256) void k_out(const float* __restrict__ S,
                                             const float* __restrict__ HW5,
                                             const float* __restrict__ b5,
                                             float* __restrict__ out) {
    __shared__ float hw[160];
    __shared__ float bb[20];
    int t = threadIdx.x;
    if (t < 160) hw[t] = HW5[t];
    if (t < 20) bb[t] = b5[t];
    __syncthreads();
    int n = blockIdx.x * 256 + t;
    if (n >= NN) return;
    const float4* sp = (const float4*)(S + n * 8);
    float4 s0 = sp[0], s1 = sp[1];
    float sv[8] = {s0.x, s0.y, s0.z, s0.w, s1.x, s1.y, s1.z, s1.w};
    float pre[20];
    #pragma unroll
    for (int c = 0; c < 20; ++c) {
        float acc = bb[c];
        #pragma unroll
        for (int g = 0; g < 8; ++g) acc += sv[g] * hw[g * 20 + c];
        pre[c] = acc;
    }
    float mx = pre[0];
    #pragma unroll
    for (int c = 1; c < 20; ++c) mx = fmaxf(mx, pre[c]);
    float sum = 0.f;
    #pragma unroll
    for (int c = 0; c < 20; ++c) { pre[c] = __expf(pre[c] - mx); sum += pre[c]; }
    float inv = 1.f / sum;
    #pragma unroll
    for (int c = 0; c < 20; ++c) out[n * 20 + c] = pre[c] * inv;
}

extern "C" void kernel_launch(void* const* d_in, const int* in_sizes, int n_in,
                              void* d_out, int out_size, void* d_ws, size_t ws_size,
                              hipStream_t stream) {
    const float* x   = (const float*)d_in[0];
    const float* ew  = (const float*)d_in[1];
    const int*   src = (const int*)d_in[2];
    const int*   dst = (const int*)d_in[3];
    const int*   ids = (const int*)d_in[4];
    const float* W1 = (const float*)d_in[5];  const float* b1 = (const float*)d_in[6];
    const float* W2 = (const float*)d_in[7];  const float* b2 = (const float*)d_in[8];
    const float* g1 = (const float*)d_in[9];  const float* be1 = (const float*)d_in[10];
    const float* m1 = (const float*)d_in[11]; const float* v1 = (const float*)d_in[12];
    const float* W3 = (const float*)d_in[13]; const float* b3 = (const float*)d_in[14];
    const float* W4 = (const float*)d_in[15]; const float* b4 = (const float*)d_in[16];
    const float* g2 = (const float*)d_in[17]; const float* be2 = (const float*)d_in[18];
    const float* m2 = (const float*)d_in[19]; const float* v2 = (const float*)d_in[20];
    const float* W5 = (const float*)d_in[21]; const float* b5 = (const float*)d_in[22];
    float* out = (float*)d_out;

    // workspace layout (~36 MB)
    char* p = (char*)d_ws;
    float*  S    = (float*)p;  p += (size_t)NN * 8 * 4;      // 2.56 MB
    ushort* T    = (ushort*)p; p += (size_t)NN * 64 * 2;     // tmp2 / tmp4 (bf16)
    float*  AX   = (float*)p;  p += (size_t)NN * 4 * 4;
    int*    rp   = (int*)p;    p += (size_t)(NN + 16) * 4;
    int*    bcnt = (int*)p;    p += 512 * 4;
    int*    bo   = (int*)p;    p += 512 * 4;
    int*    bcur = (int*)p;    p += 512 * 4;
    int2*   cB   = (int2*)p;   p += (size_t)NE * 8;          // 10.24 MB
    int2*   cE   = (int2*)p;   p += (size_t)NE * 8;          // 10.24 MB
    unsigned* MXE1 = (unsigned*)p; p += 256 * 4;
    unsigned* MXE2 = (unsigned*)p; p += 512 * 4;             // contiguous w/ MXE1
    float*  HW3  = (float*)p;  p += 512 * 4;
    float*  HW5  = (float*)p;  p += 256 * 4;

    const int BS = 256;
    const int gN = (NN + BS - 1) / BS;

    // ---- CSR build via 2-level counting sort ----
    hipMemsetAsync(bcnt, 0, 512 * 4, stream);
    hipMemsetAsync(MXE1, 0, 768 * 4, stream);   // MXE1+MXE2
    hipLaunchKernelGGL(k_bhist, dim3(GB), dim3(BS), 0, stream, dst, bcnt);
    hipLaunchKernelGGL(k_bscan, dim3(1), dim3(512), 0, stream, bcnt, bo, bcur);
    hipLaunchKernelGGL(k_bfill, dim3(GB), dim3(BS), 0, stream, src, dst, ew, ids, bcur, cB);
    hipLaunchKernelGGL(k_insort, dim3(NB), dim3(BS), 0, stream, bo, cB, rp, cE);

    // ---- fused S + aggX gather ----
    hipLaunchKernelGGL(k_gSX, dim3(gN), dim3(BS), 0, stream, x, rp, cE, S, AX);

    // ---- layers 1+2 dense fused: tmp2(T) = relu(AX@W1+b1)@W2 ----
    hipLaunchKernelGGL(k_l12, dim3(NN / 8), dim3(BS), 0, stream, AX, W1, b1, W2, T);
    hipLaunchKernelGGL(k_gpool<5>, dim3(NN / 64), dim3(BS), 0, stream, T, rp, cE, ids, b2, g1, be1, m1, v1, MXE1);

    // ---- layers 3+4: HW3 = dec(MXE1)@W3; tmp4(T) = relu(S@HW3+b3)@W4 ----
    hipLaunchKernelGGL(k_dechw3, dim3(1), dim3(512), 0, stream, MXE1, W3, HW3);
    hipLaunchKernelGGL(k_l34, dim3(NN / 4), dim3(BS), 0, stream, S, HW3, b3, W4, T);
    hipLaunchKernelGGL(k_gpool<6>, dim3(NN / 32), dim3(BS), 0, stream, T, rp, cE, ids, b4, g2, be2, m2, v2, MXE2);

    // ---- layer 5 (collapsed): HW5 = dec(MXE2)@W5; out = softmax(S@HW5+b5) ----
    hipLaunchKernelGGL(k_dechw5, dim3(1), dim3(512), 0, stream, MXE2, W5, HW5);
    hipLaunchKernelGGL(k_out, dim3(gN), dim3(BS), 0, stream, S, HW5, b5, out);
}

// Round 7
// 276.002 us; speedup vs baseline: 5.6236x; 1.1487x over previous
//
#include <hip/hip_runtime.h>

#define NN 80000
#define NE 1280000
#define NGR 8
#define BN_EPS 1e-3f
#define NB 313      // ceil(NN/256) coarse dst-buckets
#define GB 320      // blocks for bhist/bfill
#define CHK 4000    // edges per block (GB*CHK == NE)

typedef unsigned short ushort;
typedef __attribute__((ext_vector_type(8))) short bf16x8;
typedef __attribute__((ext_vector_type(4))) float f32x4;

// ---------------- order-preserving float <-> unsigned encoding ----------------
__device__ __forceinline__ unsigned enc_f(float f) {
    unsigned b = __float_as_uint(f);
    return (f >= 0.f) ? (b | 0x80000000u) : ~b;
}
__device__ __forceinline__ float dec_f(unsigned u) {
    return (u & 0x80000000u) ? __uint_as_float(u & 0x7FFFFFFFu) : __uint_as_float(~u);
}
// fp32 -> bf16 (round-to-nearest-even)
__device__ __forceinline__ ushort f2bf(float f) {
    unsigned u = __float_as_uint(f);
    unsigned r = u + 0x7FFFu + ((u >> 16) & 1u);
    return (ushort)(r >> 16);
}
// 8 bf16 (16B) fused-multiply-accumulate into fp32 acc[8]
__device__ __forceinline__ void fma8(float* acc, const ushort* p, float w) {
    uint4 q = *(const uint4*)p;
    acc[0] += w * __uint_as_float((q.x & 0xFFFFu) << 16);
    acc[1] += w * __uint_as_float(q.x & 0xFFFF0000u);
    acc[2] += w * __uint_as_float((q.y & 0xFFFFu) << 16);
    acc[3] += w * __uint_as_float(q.y & 0xFFFF0000u);
    acc[4] += w * __uint_as_float((q.z & 0xFFFFu) << 16);
    acc[5] += w * __uint_as_float(q.z & 0xFFFF0000u);
    acc[6] += w * __uint_as_float((q.w & 0xFFFFu) << 16);
    acc[7] += w * __uint_as_float(q.w & 0xFFFF0000u);
}

// ================= CSR build: 2-level counting sort =================
__global__ __launch_bounds__(256) void k_bhist(const int* __restrict__ dst,
                                               int* __restrict__ bcnt) {
    __shared__ int lh[NB];
    for (int i = threadIdx.x; i < NB; i += 256) lh[i] = 0;
    __syncthreads();
    int e0 = blockIdx.x * CHK;
    for (int e = e0 + threadIdx.x; e < e0 + CHK; e += 256)
        atomicAdd(&lh[dst[e] >> 8], 1);
    __syncthreads();
    for (int i = threadIdx.x; i < NB; i += 256) {
        int c = lh[i];
        if (c) atomicAdd(&bcnt[i], c);
    }
}

__global__ __launch_bounds__(512) void k_bscan(const int* __restrict__ bcnt,
                                               int* __restrict__ bo,
                                               int* __restrict__ bcur) {
    __shared__ int sm[512];
    int tid = threadIdx.x;
    int v = (tid < NB) ? bcnt[tid] : 0;
    sm[tid] = v;
    __syncthreads();
    #pragma unroll
    for (int off = 1; off < 512; off <<= 1) {
        int t2 = (tid >= off) ? sm[tid - off] : 0;
        __syncthreads();
        sm[tid] += t2;
        __syncthreads();
    }
    if (tid < NB) {
        int ex = sm[tid] - v;
        bo[tid] = ex;
        bcur[tid] = ex;
    }
    if (tid == 0) bo[NB] = NE;
}

__global__ __launch_bounds__(256) void k_bfill(const int* __restrict__ src,
                                               const int* __restrict__ dst,
                                               const float* __restrict__ ew,
                                               const int* __restrict__ ids,
                                               int* __restrict__ bcur,
                                               int2* __restrict__ cB) {
    __shared__ int lh[NB];
    __shared__ int lbase[NB];
    for (int i = threadIdx.x; i < NB; i += 256) lh[i] = 0;
    __syncthreads();
    int e0 = blockIdx.x * CHK;
    for (int e = e0 + threadIdx.x; e < e0 + CHK; e += 256)
        atomicAdd(&lh[dst[e] >> 8], 1);
    __syncthreads();
    for (int i = threadIdx.x; i < NB; i += 256) {
        int c = lh[i];
        lbase[i] = c ? atomicAdd(&bcur[i], c) : 0;
        lh[i] = 0;
    }
    __syncthreads();
    for (int e = e0 + threadIdx.x; e < e0 + CHK; e += 256) {
        int d = dst[e];
        int b = d >> 8;
        int s = src[e];
        int pos = lbase[b] + atomicAdd(&lh[b], 1);
        cB[pos] = make_int2(s | (ids[s] << 17) | ((d & 255) << 20),
                            __float_as_int(ew[e]));
    }
}

__global__ __launch_bounds__(256) void k_insort(const int* __restrict__ bo,
                                                const int2* __restrict__ cB,
                                                int* __restrict__ rp,
                                                int2* __restrict__ cE) {
    __shared__ int lc[256];
    __shared__ int loff[256];
    __shared__ int sm[256];
    int b = blockIdx.x, tid = threadIdx.x;
    int s0 = bo[b], s1 = bo[b + 1];
    lc[tid] = 0;
    __syncthreads();
    for (int i = s0 + tid; i < s1; i += 256)
        atomicAdd(&lc[(cB[i].x >> 20) & 255], 1);
    __syncthreads();
    int v = lc[tid];
    sm[tid] = v;
    __syncthreads();
    #pragma unroll
    for (int off = 1; off < 256; off <<= 1) {
        int t2 = (tid >= off) ? sm[tid - off] : 0;
        __syncthreads();
        sm[tid] += t2;
        __syncthreads();
    }
    loff[tid] = sm[tid] - v;
    int n = b * 256 + tid;
    if (n < NN) rp[n] = s0 + loff[tid];
    if (b == NB - 1 && tid == 0) rp[NN] = NE;
    lc[tid] = 0;
    __syncthreads();
    for (int i = s0 + tid; i < s1; i += 256) {
        int2 a = cB[i];
        int dlow = (a.x >> 20) & 255;
        int pos = s0 + loff[dlow] + atomicAdd(&lc[dlow], 1);
        cE[pos] = make_int2((a.x & 0x1FFFF) | (((a.x >> 17) & 7) << 24), a.y);
    }
}

// ---- weight prep: bf16 transposed W2t[f][k], W4t[f][k] ----
__global__ __launch_bounds__(256) void k_wprep(const float* __restrict__ W2,
                                               const float* __restrict__ W4,
                                               ushort* __restrict__ W2t,
                                               ushort* __restrict__ W4t) {
    int t = threadIdx.x;
    for (int i = t; i < 32 * 32; i += 256) {
        int f = i >> 5, k = i & 31;
        W2t[i] = f2bf(W2[k * 32 + f]);
    }
    for (int i = t; i < 64 * 64; i += 256) {
        int f = i >> 6, k = i & 63;
        W4t[i] = f2bf(W4[k * 64 + f]);
    }
}

// ================= fused S + aggX gather (one thread per node) =================
__global__ __launch_bounds__(256) void k_gSX(const float* __restrict__ x,
                                             const int* __restrict__ rp,
                                             const int2* __restrict__ cE,
                                             float* __restrict__ S,
                                             float* __restrict__ AX) {
    int n = blockIdx.x * 256 + threadIdx.x;
    if (n >= NN) return;
    int e0 = rp[n], e1 = rp[n + 1];
    float sv[8] = {0, 0, 0, 0, 0, 0, 0, 0};
    float ax0 = 0.f, ax1 = 0.f, ax2 = 0.f;
    for (int i = e0; i < e1; ++i) {
        int2 a = cE[i];
        float w = __int_as_float(a.y);
        int s = a.x & 0xFFFFFF;
        int gg = a.x >> 24;
        #pragma unroll
        for (int g = 0; g < 8; ++g) sv[g] += (gg == g) ? w : 0.f;
        const float* xp = x + s * 3;
        ax0 += w * xp[0]; ax1 += w * xp[1]; ax2 += w * xp[2];
    }
    float4* Sp = (float4*)(S + n * 8);
    Sp[0] = make_float4(sv[0], sv[1], sv[2], sv[3]);
    Sp[1] = make_float4(sv[4], sv[5], sv[6], sv[7]);
    *(float4*)(AX + n * 4) = make_float4(ax0, ax1, ax2, 0.f);
}

// ======== MFMA fused l1+l2: tmp2 = bf16(relu(AX@W1+b1)) @ bf16(W2) ========
// 64 nodes/block; h1 staged bf16 in LDS (stride 40 shorts: 16B-aligned, 2-way banks)
__global__ __launch_bounds__(256) void k_l12m(const float* __restrict__ AX,
                                              const float* __restrict__ W1,
                                              const float* __restrict__ b1,
                                              const ushort* __restrict__ W2t,
                                              ushort* __restrict__ T) {
    __shared__ ushort h1s[64 * 40];
    int t = threadIdx.x;
    int nb = blockIdx.x * 64;
    // stage 1: h1 = relu(AX@W1+b1) -> bf16 LDS
    {
        int f = t & 31, rr = t >> 5;               // 8 node-groups
        float w0 = W1[f], w1 = W1[32 + f], w2 = W1[64 + f], bb = b1[f];
        #pragma unroll
        for (int i = 0; i < 8; ++i) {
            int n = rr + i * 8;
            float4 ax = *(const float4*)(AX + (nb + n) * 4);
            float acc = bb + ax.x * w0 + ax.y * w1 + ax.z * w2;
            h1s[n * 40 + f] = f2bf(fmaxf(acc, 0.f));
        }
    }
    __syncthreads();
    // stage 2: MFMA 16x16x32, 4 m-tiles x 2 n-tiles; wave w -> mtile w
    int lane = t & 63, wave = t >> 6;
    int quad = lane >> 4, col = lane & 15;
    int mtile = wave;
    bf16x8 a = *(const bf16x8*)(h1s + (mtile * 16 + col) * 40 + quad * 8);
    #pragma unroll
    for (int ntile = 0; ntile < 2; ++ntile) {
        bf16x8 b = *(const bf16x8*)(W2t + (ntile * 16 + col) * 32 + quad * 8);
        f32x4 acc = {0.f, 0.f, 0.f, 0.f};
        acc = __builtin_amdgcn_mfma_f32_16x16x32_bf16(a, b, acc, 0, 0, 0);
        #pragma unroll
        for (int r = 0; r < 4; ++r) {
            int node = nb + mtile * 16 + quad * 4 + r;
            T[node * 32 + ntile * 16 + col] = f2bf(acc[r]);
        }
    }
}

// ======== MFMA fused l3+l4: tmp4 = bf16(relu(S@HW3+b3)) @ bf16(W4) ========
// 64 nodes/block; h3 staged bf16 in LDS (stride 72 shorts)
__global__ __launch_bounds__(256) void k_l34m(const float* __restrict__ S,
                                              const float* __restrict__ HW3,
                                              const float* __restrict__ b3,
                                              const ushort* __restrict__ W4t,
                                              ushort* __restrict__ T) {
    __shared__ ushort h3s[64 * 72];
    int t = threadIdx.x;
    int nb = blockIdx.x * 64;
    // stage 1: h3 = relu(S@HW3+b3) -> bf16 LDS
    {
        int f = t & 63, rr = t >> 6;               // 4 node-groups
        float hwc[8];
        #pragma unroll
        for (int g = 0; g < 8; ++g) hwc[g] = HW3[g * 64 + f];
        float bb = b3[f];
        #pragma unroll
        for (int i = 0; i < 16; ++i) {
            int n = rr + i * 4;
            const float4* sp = (const float4*)(S + (size_t)(nb + n) * 8);
            float4 s0 = sp[0], s1 = sp[1];
            float acc = bb + s0.x * hwc[0] + s0.y * hwc[1] + s0.z * hwc[2] +
                        s0.w * hwc[3] + s1.x * hwc[4] + s1.y * hwc[5] +
                        s1.z * hwc[6] + s1.w * hwc[7];
            h3s[n * 72 + f] = f2bf(fmaxf(acc, 0.f));
        }
    }
    __syncthreads();
    // stage 2: MFMA 16x16x32 x2 k-chunks; 4 m-tiles x 4 n-tiles
    int lane = t & 63, wave = t >> 6;
    int quad = lane >> 4, col = lane & 15;
    int mtile = wave;
    bf16x8 a0 = *(const bf16x8*)(h3s + (mtile * 16 + col) * 72 + quad * 8);
    bf16x8 a1 = *(const bf16x8*)(h3s + (mtile * 16 + col) * 72 + 32 + quad * 8);
    #pragma unroll
    for (int ntile = 0; ntile < 4; ++ntile) {
        bf16x8 b0 = *(const bf16x8*)(W4t + (ntile * 16 + col) * 64 + quad * 8);
        bf16x8 b1v = *(const bf16x8*)(W4t + (ntile * 16 + col) * 64 + 32 + quad * 8);
        f32x4 acc = {0.f, 0.f, 0.f, 0.f};
        acc = __builtin_amdgcn_mfma_f32_16x16x32_bf16(a0, b0, acc, 0, 0, 0);
        acc = __builtin_amdgcn_mfma_f32_16x16x32_bf16(a1, b1v, acc, 0, 0, 0);
        #pragma unroll
        for (int r = 0; r < 4; ++r) {
            int node = nb + mtile * 16 + quad * 4 + r;
            T[node * 64 + ntile * 16 + col] = f2bf(acc[r]);
        }
    }
}

// ---- fused gather (bf16 rows) + bias + relu + BN + per-graph max pool ----
template <int LOGF>
__global__ __launch_bounds__(256) void k_gpool(const ushort* __restrict__ th,
                                               const int* __restrict__ rp,
                                               const int2* __restrict__ cE,
                                               const int* __restrict__ ids,
                                               const float* __restrict__ b,
                                               const float* __restrict__ g,
                                               const float* __restrict__ be,
                                               const float* __restrict__ m,
                                               const float* __restrict__ v,
                                               unsigned* __restrict__ mxe) {
    const int F = 1 << LOGF;
    const int CPN = F >> 3;
    const int NPB = 256 / CPN;
    __shared__ unsigned lmx[NGR * F];
    for (int i = threadIdx.x; i < NGR * F; i += 256) lmx[i] = 0u;
    __syncthreads();
    int c = threadIdx.x & (CPN - 1);
    int n = blockIdx.x * NPB + (threadIdx.x >> (LOGF - 3));
    if (n < NN) {
        int e0 = rp[n], e1 = rp[n + 1];
        float acc[8] = {0, 0, 0, 0, 0, 0, 0, 0};
        float acc2[8] = {0, 0, 0, 0, 0, 0, 0, 0};
        int i = e0;
        for (; i + 2 <= e1; i += 2) {
            int2 a0 = cE[i], a1 = cE[i + 1];
            const ushort* p0 = th + (((size_t)(a0.x & 0xFFFFFF)) << LOGF) + (c << 3);
            const ushort* p1 = th + (((size_t)(a1.x & 0xFFFFFF)) << LOGF) + (c << 3);
            fma8(acc, p0, __int_as_float(a0.y));
            fma8(acc2, p1, __int_as_float(a1.y));
        }
        if (i < e1) {
            int2 a0 = cE[i];
            fma8(acc, th + (((size_t)(a0.x & 0xFFFFFF)) << LOGF) + (c << 3),
                 __int_as_float(a0.y));
        }
        int gg = ids[n];
        #pragma unroll
        for (int j = 0; j < 8; ++j) {
            int f = (c << 3) + j;
            float scale = g[f] * rsqrtf(v[f] + BN_EPS);
            float h = fmaxf(acc[j] + acc2[j] + b[f], 0.f);
            float val = (h - m[f]) * scale + be[f];
            atomicMax(&lmx[gg * F + f], enc_f(val));
        }
    }
    __syncthreads();
    for (int i = threadIdx.x; i < NGR * F; i += 256) {
        unsigned u = lmx[i];
        if (u) atomicMax(&mxe[i], u);
    }
}

// decode MXE1 (256) + HW3 = MX1@W3, one block 512
__global__ __launch_bounds__(512) void k_dechw3(const unsigned* __restrict__ mxe,
                                                const float* __restrict__ W,
                                                float* __restrict__ HW) {
    __shared__ float smx[256];
    int t = threadIdx.x;
    if (t < 256) smx[t] = mxe[t] ? dec_f(mxe[t]) : 0.f;
    __syncthreads();
    int g = t >> 6, f = t & 63;
    float acc = 0.f;
    #pragma unroll
    for (int k = 0; k < 32; ++k) acc += smx[g * 32 + k] * W[k * 64 + f];
    HW[t] = acc;
}

// decode MXE2 (512) + HW5 = MX2@W5, one block 512
__global__ __launch_bounds__(512) void k_dechw5(const unsigned* __restrict__ mxe,
                                                const float* __restrict__ W,
                                                float* __restrict__ HW) {
    __shared__ float smx[512];
    int t = threadIdx.x;
    smx[t] = mxe[t] ? dec_f(mxe[t]) : 0.f;
    __syncthreads();
    if (t >= 160) return;
    int g = t / 20, c = t % 20;
    float acc = 0.f;
    #pragma unroll
    for (int k = 0; k < 64; ++k) acc += smx[g * 64 + k] * W[k * 20 + c];
    HW[t] = acc;
}

__global__ __launch_bounds__(256) void k_out(const float* __restrict__ S,
                                             const float* __restrict__ HW5,
                                             const float* __restrict__ b5,
                                             float* __restrict__ out) {
    __shared__ float hw[160];
    __shared__ float bb[20];
    int t = threadIdx.x;
    if (t < 160) hw[t] = HW5[t];
    if (t < 20) bb[t] = b5[t];
    __syncthreads();
    int n = blockIdx.x * 256 + t;
    if (n >= NN) return;
    const float4* sp = (const float4*)(S + n * 8);
    float4 s0 = sp[0], s1 = sp[1];
    float sv[8] = {s0.x, s0.y, s0.z, s0.w, s1.x, s1.y, s1.z, s1.w};
    float pre[20];
    #pragma unroll
    for (int c = 0; c < 20; ++c) {
        float acc = bb[c];
        #pragma unroll
        for (int g = 0; g < 8; ++g) acc += sv[g] * hw[g * 20 + c];
        pre[c] = acc;
    }
    float mx = pre[0];
    #pragma unroll
    for (int c = 1; c < 20; ++c) mx = fmaxf(mx, pre[c]);
    float sum = 0.f;
    #pragma unroll
    for (int c = 0; c < 20; ++c) { pre[c] = __expf(pre[c] - mx); sum += pre[c]; }
    float inv = 1.f / sum;
    #pragma unroll
    for (int c = 0; c < 20; ++c) out[n * 20 + c] = pre[c] * inv;
}

extern "C" void kernel_launch(void* const* d_in, const int* in_sizes, int n_in,
                              void* d_out, int out_size, void* d_ws, size_t ws_size,
                              hipStream_t stream) {
    const float* x   = (const float*)d_in[0];
    const float* ew  = (const float*)d_in[1];
    const int*   src = (const int*)d_in[2];
    const int*   dst = (const int*)d_in[3];
    const int*   ids = (const int*)d_in[4];
    const float* W1 = (const float*)d_in[5];  const float* b1 = (const float*)d_in[6];
    const float* W2 = (const float*)d_in[7];  const float* b2 = (const float*)d_in[8];
    const float* g1 = (const float*)d_in[9];  const float* be1 = (const float*)d_in[10];
    const float* m1 = (const float*)d_in[11]; const float* v1 = (const float*)d_in[12];
    const float* W3 = (const float*)d_in[13]; const float* b3 = (const float*)d_in[14];
    const float* W4 = (const float*)d_in[15]; const float* b4 = (const float*)d_in[16];
    const float* g2 = (const float*)d_in[17]; const float* be2 = (const float*)d_in[18];
    const float* m2 = (const float*)d_in[19]; const float* v2 = (const float*)d_in[20];
    const float* W5 = (const float*)d_in[21]; const float* b5 = (const float*)d_in[22];
    float* out = (float*)d_out;

    // workspace layout (~36 MB)
    char* p = (char*)d_ws;
    float*  S    = (float*)p;  p += (size_t)NN * 8 * 4;
    ushort* T    = (ushort*)p; p += (size_t)NN * 64 * 2;
    float*  AX   = (float*)p;  p += (size_t)NN * 4 * 4;
    int*    rp   = (int*)p;    p += (size_t)(NN + 16) * 4;
    int*    bcnt = (int*)p;    p += 512 * 4;
    int*    bo   = (int*)p;    p += 512 * 4;
    int*    bcur = (int*)p;    p += 512 * 4;
    int2*   cB   = (int2*)p;   p += (size_t)NE * 8;
    int2*   cE   = (int2*)p;   p += (size_t)NE * 8;
    unsigned* MXE1 = (unsigned*)p; p += 256 * 4;
    unsigned* MXE2 = (unsigned*)p; p += 512 * 4;
    float*  HW3  = (float*)p;  p += 512 * 4;
    float*  HW5  = (float*)p;  p += 256 * 4;
    ushort* W2t  = (ushort*)p; p += 1024 * 2;
    ushort* W4t  = (ushort*)p; p += 4096 * 2;

    const int BS = 256;
    const int gN = (NN + BS - 1) / BS;

    // ---- CSR build via 2-level counting sort + weight prep ----
    hipMemsetAsync(bcnt, 0, 512 * 4, stream);
    hipMemsetAsync(MXE1, 0, 768 * 4, stream);
    hipLaunchKernelGGL(k_wprep, dim3(1), dim3(BS), 0, stream, W2, W4, W2t, W4t);
    hipLaunchKernelGGL(k_bhist, dim3(GB), dim3(BS), 0, stream, dst, bcnt);
    hipLaunchKernelGGL(k_bscan, dim3(1), dim3(512), 0, stream, bcnt, bo, bcur);
    hipLaunchKernelGGL(k_bfill, dim3(GB), dim3(BS), 0, stream, src, dst, ew, ids, bcur, cB);
    hipLaunchKernelGGL(k_insort, dim3(NB), dim3(BS), 0, stream, bo, cB, rp, cE);

    // ---- fused S + aggX gather ----
    hipLaunchKernelGGL(k_gSX, dim3(gN), dim3(BS), 0, stream, x, rp, cE, S, AX);

    // ---- layers 1+2 (MFMA): tmp2(T) = relu(AX@W1+b1)@W2 ----
    hipLaunchKernelGGL(k_l12m, dim3(NN / 64), dim3(BS), 0, stream, AX, W1, b1, W2t, T);
    hipLaunchKernelGGL(k_gpool<5>, dim3(NN / 64), dim3(BS), 0, stream, T, rp, cE, ids, b2, g1, be1, m1, v1, MXE1);

    // ---- layers 3+4 (MFMA): HW3 = dec(MXE1)@W3; tmp4(T) = relu(S@HW3+b3)@W4 ----
    hipLaunchKernelGGL(k_dechw3, dim3(1), dim3(512), 0, stream, MXE1, W3, HW3);
    hipLaunchKernelGGL(k_l34m, dim3(NN / 64), dim3(BS), 0, stream, S, HW3, b3, W4t, T);
    hipLaunchKernelGGL(k_gpool<6>, dim3(NN / 32), dim3(BS), 0, stream, T, rp, cE, ids, b4, g2, be2, m2, v2, MXE2);

    // ---- layer 5 (collapsed): HW5 = dec(MXE2)@W5; out = softmax(S@HW5+b5) ----
    hipLaunchKernelGGL(k_dechw5, dim3(1), dim3(512), 0, stream, MXE2, W5, HW5);
    hipLaunchKernelGGL(k_out, dim3(gN), dim3(BS), 0, stream, S, HW5, b5, out);
}

// Round 8
// 274.108 us; speedup vs baseline: 5.6624x; 1.0069x over previous
//
#include <hip/hip_runtime.h>

#define NN 80000
#define NE 1280000
#define NGR 8
#define BN_EPS 1e-3f
#define NBF 625     // fine dst-buckets (128 nodes each; 625*128 == NN)
#define GB 1280     // blocks for bhist/bfill
#define CHK 1000    // edges per block (GB*CHK == NE)

typedef unsigned short ushort;
typedef __attribute__((ext_vector_type(8))) short bf16x8;
typedef __attribute__((ext_vector_type(4))) float f32x4;

// ---------------- order-preserving float <-> unsigned encoding ----------------
__device__ __forceinline__ unsigned enc_f(float f) {
    unsigned b = __float_as_uint(f);
    return (f >= 0.f) ? (b | 0x80000000u) : ~b;
}
__device__ __forceinline__ float dec_f(unsigned u) {
    return (u & 0x80000000u) ? __uint_as_float(u & 0x7FFFFFFFu) : __uint_as_float(~u);
}
// fp32 -> bf16 (round-to-nearest-even)
__device__ __forceinline__ ushort f2bf(float f) {
    unsigned u = __float_as_uint(f);
    unsigned r = u + 0x7FFFu + ((u >> 16) & 1u);
    return (ushort)(r >> 16);
}
// 8 bf16 (16B) fused-multiply-accumulate into fp32 acc[8]
__device__ __forceinline__ void fma8(float* acc, const ushort* p, float w) {
    uint4 q = *(const uint4*)p;
    acc[0] += w * __uint_as_float((q.x & 0xFFFFu) << 16);
    acc[1] += w * __uint_as_float(q.x & 0xFFFF0000u);
    acc[2] += w * __uint_as_float((q.y & 0xFFFFu) << 16);
    acc[3] += w * __uint_as_float(q.y & 0xFFFF0000u);
    acc[4] += w * __uint_as_float((q.z & 0xFFFFu) << 16);
    acc[5] += w * __uint_as_float(q.z & 0xFFFF0000u);
    acc[6] += w * __uint_as_float((q.w & 0xFFFFu) << 16);
    acc[7] += w * __uint_as_float(q.w & 0xFFFF0000u);
}

// ================= CSR build: counting sort w/ precomputed bases =================
// Pass A: per-block LDS histogram over 625 fine buckets -> hcnt[block][bin] (no atomics)
__global__ __launch_bounds__(256) void k_bhist(const int* __restrict__ dst,
                                               int* __restrict__ hcnt) {
    __shared__ int lh[NBF];
    for (int i = threadIdx.x; i < NBF; i += 256) lh[i] = 0;
    __syncthreads();
    int e0 = blockIdx.x * CHK;
    for (int e = e0 + threadIdx.x; e < e0 + CHK; e += 256)
        atomicAdd(&lh[dst[e] >> 7], 1);
    __syncthreads();
    int* row = hcnt + (size_t)blockIdx.x * NBF;
    for (int i = threadIdx.x; i < NBF; i += 256) row[i] = lh[i];
}

// Pass B1: per-bin exclusive scan across the 1280 blocks (in-place), bin totals out
__global__ __launch_bounds__(256) void k_bbase1(int* __restrict__ hcnt,
                                                int* __restrict__ tot) {
    __shared__ int sm[256];
    int bin = blockIdx.x, t = threadIdx.x;
    int v[5];
    int s = 0;
    #pragma unroll
    for (int j = 0; j < 5; ++j) {
        v[j] = hcnt[(size_t)(t * 5 + j) * NBF + bin];
        s += v[j];
    }
    sm[t] = s;
    __syncthreads();
    #pragma unroll
    for (int off = 1; off < 256; off <<= 1) {
        int u = (t >= off) ? sm[t - off] : 0;
        __syncthreads();
        sm[t] += u;
        __syncthreads();
    }
    int run = sm[t] - s;
    if (t == 255) tot[bin] = sm[255];
    #pragma unroll
    for (int j = 0; j < 5; ++j) {
        hcnt[(size_t)(t * 5 + j) * NBF + bin] = run;
        run += v[j];
    }
}

// Pass B2: exclusive scan of 625 bin totals -> bo
__global__ __launch_bounds__(1024) void k_bbase2(const int* __restrict__ tot,
                                                 int* __restrict__ bo) {
    __shared__ int sm[1024];
    int t = threadIdx.x;
    int v = (t < NBF) ? tot[t] : 0;
    sm[t] = v;
    __syncthreads();
    #pragma unroll
    for (int off = 1; off < 1024; off <<= 1) {
        int u = (t >= off) ? sm[t - off] : 0;
        __syncthreads();
        sm[t] += u;
        __syncthreads();
    }
    if (t < NBF) bo[t] = sm[t] - v;
    if (t == 0) bo[NBF] = NE;
}

// Pass C: bucket edges; cursors = precomputed base (no global atomics).
// Payload: src(17b) | g(3b,@17) | dlow(7b,@20)
__global__ __launch_bounds__(256) void k_bfill(const int* __restrict__ src,
                                               const int* __restrict__ dst,
                                               const float* __restrict__ ew,
                                               const int* __restrict__ ids,
                                               const int* __restrict__ hcnt,
                                               const int* __restrict__ bo,
                                               int2* __restrict__ cB) {
    __shared__ int lcur[NBF];
    const int* row = hcnt + (size_t)blockIdx.x * NBF;
    for (int i = threadIdx.x; i < NBF; i += 256) lcur[i] = row[i] + bo[i];
    __syncthreads();
    int e0 = blockIdx.x * CHK;
    for (int e = e0 + threadIdx.x; e < e0 + CHK; e += 256) {
        int d = dst[e];
        int s = src[e];
        int pos = atomicAdd(&lcur[d >> 7], 1);
        cB[pos] = make_int2(s | (ids[s] << 17) | ((d & 127) << 20),
                            __float_as_int(ew[e]));
    }
}

// Pass D: one block per fine bucket (128 nodes): LDS counting sort by dlow,
// emits rp and final cE (src | g<<24, w). Zero global atomics.
__global__ __launch_bounds__(512) void k_insort(const int* __restrict__ bo,
                                                const int2* __restrict__ cB,
                                                int* __restrict__ rp,
                                                int2* __restrict__ cE) {
    __shared__ int lc[128];
    __shared__ int loff[128];
    __shared__ int sm[512];
    int bin = blockIdx.x, t = threadIdx.x;
    int s0 = bo[bin], s1 = bo[bin + 1];
    if (t < 128) lc[t] = 0;
    __syncthreads();
    for (int i = s0 + t; i < s1; i += 512)
        atomicAdd(&lc[(cB[i].x >> 20) & 127], 1);
    __syncthreads();
    int v = (t < 128) ? lc[t] : 0;
    sm[t] = v;
    __syncthreads();
    #pragma unroll
    for (int off = 1; off < 128; off <<= 1) {
        int u = (t >= off && t < 128) ? sm[t - off] : 0;
        __syncthreads();
        if (t < 128) sm[t] += u;
        __syncthreads();
    }
    if (t < 128) {
        loff[t] = sm[t] - v;
        rp[bin * 128 + t] = s0 + loff[t];
        lc[t] = 0;
    }
    if (bin == NBF - 1 && t == 0) rp[NN] = NE;
    __syncthreads();
    for (int i = s0 + t; i < s1; i += 512) {
        int2 a = cB[i];
        int dlow = (a.x >> 20) & 127;
        int pos = s0 + loff[dlow] + atomicAdd(&lc[dlow], 1);
        cE[pos] = make_int2((a.x & 0x1FFFF) | (((a.x >> 17) & 7) << 24), a.y);
    }
}

// ---- weight prep: bf16 transposed W2t[f][k], W4t[f][k] ----
__global__ __launch_bounds__(256) void k_wprep(const float* __restrict__ W2,
                                               const float* __restrict__ W4,
                                               ushort* __restrict__ W2t,
                                               ushort* __restrict__ W4t) {
    int t = threadIdx.x;
    for (int i = t; i < 32 * 32; i += 256) {
        int f = i >> 5, k = i & 31;
        W2t[i] = f2bf(W2[k * 32 + f]);
    }
    for (int i = t; i < 64 * 64; i += 256) {
        int f = i >> 6, k = i & 63;
        W4t[i] = f2bf(W4[k * 64 + f]);
    }
}

// ================= fused S + aggX gather (one thread per node) =================
__global__ __launch_bounds__(256) void k_gSX(const float* __restrict__ x,
                                             const int* __restrict__ rp,
                                             const int2* __restrict__ cE,
                                             float* __restrict__ S,
                                             float* __restrict__ AX) {
    int n = blockIdx.x * 256 + threadIdx.x;
    if (n >= NN) return;
    int e0 = rp[n], e1 = rp[n + 1];
    float sv[8] = {0, 0, 0, 0, 0, 0, 0, 0};
    float ax0 = 0.f, ax1 = 0.f, ax2 = 0.f;
    for (int i = e0; i < e1; ++i) {
        int2 a = cE[i];
        float w = __int_as_float(a.y);
        int s = a.x & 0xFFFFFF;
        int gg = a.x >> 24;
        #pragma unroll
        for (int g = 0; g < 8; ++g) sv[g] += (gg == g) ? w : 0.f;
        const float* xp = x + s * 3;
        ax0 += w * xp[0]; ax1 += w * xp[1]; ax2 += w * xp[2];
    }
    float4* Sp = (float4*)(S + n * 8);
    Sp[0] = make_float4(sv[0], sv[1], sv[2], sv[3]);
    Sp[1] = make_float4(sv[4], sv[5], sv[6], sv[7]);
    *(float4*)(AX + n * 4) = make_float4(ax0, ax1, ax2, 0.f);
}

// ======== MFMA fused l1+l2: tmp2 = bf16(relu(AX@W1+b1)) @ bf16(W2) ========
__global__ __launch_bounds__(256) void k_l12m(const float* __restrict__ AX,
                                              const float* __restrict__ W1,
                                              const float* __restrict__ b1,
                                              const ushort* __restrict__ W2t,
                                              ushort* __restrict__ T) {
    __shared__ ushort h1s[64 * 40];
    int t = threadIdx.x;
    int nb = blockIdx.x * 64;
    {
        int f = t & 31, rr = t >> 5;
        float w0 = W1[f], w1 = W1[32 + f], w2 = W1[64 + f], bb = b1[f];
        #pragma unroll
        for (int i = 0; i < 8; ++i) {
            int n = rr + i * 8;
            float4 ax = *(const float4*)(AX + (nb + n) * 4);
            float acc = bb + ax.x * w0 + ax.y * w1 + ax.z * w2;
            h1s[n * 40 + f] = f2bf(fmaxf(acc, 0.f));
        }
    }
    __syncthreads();
    int lane = t & 63, wave = t >> 6;
    int quad = lane >> 4, col = lane & 15;
    int mtile = wave;
    bf16x8 a = *(const bf16x8*)(h1s + (mtile * 16 + col) * 40 + quad * 8);
    #pragma unroll
    for (int ntile = 0; ntile < 2; ++ntile) {
        bf16x8 b = *(const bf16x8*)(W2t + (ntile * 16 + col) * 32 + quad * 8);
        f32x4 acc = {0.f, 0.f, 0.f, 0.f};
        acc = __builtin_amdgcn_mfma_f32_16x16x32_bf16(a, b, acc, 0, 0, 0);
        #pragma unroll
        for (int r = 0; r < 4; ++r) {
            int node = nb + mtile * 16 + quad * 4 + r;
            T[node * 32 + ntile * 16 + col] = f2bf(acc[r]);
        }
    }
}

// ======== MFMA fused l3+l4: tmp4 = bf16(relu(S@HW3+b3)) @ bf16(W4) ========
__global__ __launch_bounds__(256) void k_l34m(const float* __restrict__ S,
                                              const float* __restrict__ HW3,
                                              const float* __restrict__ b3,
                                              const ushort* __restrict__ W4t,
                                              ushort* __restrict__ T) {
    __shared__ ushort h3s[64 * 72];
    int t = threadIdx.x;
    int nb = blockIdx.x * 64;
    {
        int f = t & 63, rr = t >> 6;
        float hwc[8];
        #pragma unroll
        for (int g = 0; g < 8; ++g) hwc[g] = HW3[g * 64 + f];
        float bb = b3[f];
        #pragma unroll
        for (int i = 0; i < 16; ++i) {
            int n = rr + i * 4;
            const float4* sp = (const float4*)(S + (size_t)(nb + n) * 8);
            float4 s0 = sp[0], s1 = sp[1];
            float acc = bb + s0.x * hwc[0] + s0.y * hwc[1] + s0.z * hwc[2] +
                        s0.w * hwc[3] + s1.x * hwc[4] + s1.y * hwc[5] +
                        s1.z * hwc[6] + s1.w * hwc[7];
            h3s[n * 72 + f] = f2bf(fmaxf(acc, 0.f));
        }
    }
    __syncthreads();
    int lane = t & 63, wave = t >> 6;
    int quad = lane >> 4, col = lane & 15;
    int mtile = wave;
    bf16x8 a0 = *(const bf16x8*)(h3s + (mtile * 16 + col) * 72 + quad * 8);
    bf16x8 a1 = *(const bf16x8*)(h3s + (mtile * 16 + col) * 72 + 32 + quad * 8);
    #pragma unroll
    for (int ntile = 0; ntile < 4; ++ntile) {
        bf16x8 b0 = *(const bf16x8*)(W4t + (ntile * 16 + col) * 64 + quad * 8);
        bf16x8 b1v = *(const bf16x8*)(W4t + (ntile * 16 + col) * 64 + 32 + quad * 8);
        f32x4 acc = {0.f, 0.f, 0.f, 0.f};
        acc = __builtin_amdgcn_mfma_f32_16x16x32_bf16(a0, b0, acc, 0, 0, 0);
        acc = __builtin_amdgcn_mfma_f32_16x16x32_bf16(a1, b1v, acc, 0, 0, 0);
        #pragma unroll
        for (int r = 0; r < 4; ++r) {
            int node = nb + mtile * 16 + quad * 4 + r;
            T[node * 64 + ntile * 16 + col] = f2bf(acc[r]);
        }
    }
}

// ---- fused gather (bf16 rows) + bias + relu + BN + per-graph max pool ----
template <int LOGF>
__global__ __launch_bounds__(256) void k_gpool(const ushort* __restrict__ th,
                                               const int* __restrict__ rp,
                                               const int2* __restrict__ cE,
                                               const int* __restrict__ ids,
                                               const float* __restrict__ b,
                                               const float* __restrict__ g,
                                               const float* __restrict__ be,
                                               const float* __restrict__ m,
                                               const float* __restrict__ v,
                                               unsigned* __restrict__ mxe) {
    const int F = 1 << LOGF;
    const int CPN = F >> 3;
    const int NPB = 256 / CPN;
    __shared__ unsigned lmx[NGR * F];
    for (int i = threadIdx.x; i < NGR * F; i += 256) lmx[i] = 0u;
    __syncthreads();
    int c = threadIdx.x & (CPN - 1);
    int n = blockIdx.x * NPB + (threadIdx.x >> (LOGF - 3));
    if (n < NN) {
        int e0 = rp[n], e1 = rp[n + 1];
        float acc[8] = {0, 0, 0, 0, 0, 0, 0, 0};
        float acc2[8] = {0, 0, 0, 0, 0, 0, 0, 0};
        int i = e0;
        for (; i + 2 <= e1; i += 2) {
            int2 a0 = cE[i], a1 = cE[i + 1];
            const ushort* p0 = th + (((size_t)(a0.x & 0xFFFFFF)) << LOGF) + (c << 3);
            const ushort* p1 = th + (((size_t)(a1.x & 0xFFFFFF)) << LOGF) + (c << 3);
            fma8(acc, p0, __int_as_float(a0.y));
            fma8(acc2, p1, __int_as_float(a1.y));
        }
        if (i < e1) {
            int2 a0 = cE[i];
            fma8(acc, th + (((size_t)(a0.x & 0xFFFFFF)) << LOGF) + (c << 3),
                 __int_as_float(a0.y));
        }
        int gg = ids[n];
        #pragma unroll
        for (int j = 0; j < 8; ++j) {
            int f = (c << 3) + j;
            float scale = g[f] * rsqrtf(v[f] + BN_EPS);
            float h = fmaxf(acc[j] + acc2[j] + b[f], 0.f);
            float val = (h - m[f]) * scale + be[f];
            atomicMax(&lmx[gg * F + f], enc_f(val));
        }
    }
    __syncthreads();
    for (int i = threadIdx.x; i < NGR * F; i += 256) {
        unsigned u = lmx[i];
        if (u) atomicMax(&mxe[i], u);
    }
}

// decode MXE1 (256) + HW3 = MX1@W3, one block 512
__global__ __launch_bounds__(512) void k_dechw3(const unsigned* __restrict__ mxe,
                                                const float* __restrict__ W,
                                                float* __restrict__ HW) {
    __shared__ float smx[256];
    int t = threadIdx.x;
    if (t < 256) smx[t] = mxe[t] ? dec_f(mxe[t]) : 0.f;
    __syncthreads();
    int g = t >> 6, f = t & 63;
    float acc = 0.f;
    #pragma unroll
    for (int k = 0; k < 32; ++k) acc += smx[g * 32 + k] * W[k * 64 + f];
    HW[t] = acc;
}

// decode MXE2 (512) + HW5 = MX2@W5, one block 512
__global__ __launch_bounds__(512) void k_dechw5(const unsigned* __restrict__ mxe,
                                                const float* __restrict__ W,
                                                float* __restrict__ HW) {
    __shared__ float smx[512];
    int t = threadIdx.x;
    smx[t] = mxe[t] ? dec_f(mxe[t]) : 0.f;
    __syncthreads();
    if (t >= 160) return;
    int g = t / 20, c = t % 20;
    float acc = 0.f;
    #pragma unroll
    for (int k = 0; k < 64; ++k) acc += smx[g * 64 + k] * W[k * 20 + c];
    HW[t] = acc;
}

__global__ __launch_bounds__(256) void k_out(const float* __restrict__ S,
                                             const float* __restrict__ HW5,
                                             const float* __restrict__ b5,
                                             float* __restrict__ out) {
    __shared__ float hw[160];
    __shared__ float bb[20];
    int t = threadIdx.x;
    if (t < 160) hw[t] = HW5[t];
    if (t < 20) bb[t] = b5[t];
    __syncthreads();
    int n = blockIdx.x * 256 + t;
    if (n >= NN) return;
    const float4* sp = (const float4*)(S + n * 8);
    float4 s0 = sp[0], s1 = sp[1];
    float sv[8] = {s0.x, s0.y, s0.z, s0.w, s1.x, s1.y, s1.z, s1.w};
    float pre[20];
    #pragma unroll
    for (int c = 0; c < 20; ++c) {
        float acc = bb[c];
        #pragma unroll
        for (int g = 0; g < 8; ++g) acc += sv[g] * hw[g * 20 + c];
        pre[c] = acc;
    }
    float mx = pre[0];
    #pragma unroll
    for (int c = 1; c < 20; ++c) mx = fmaxf(mx, pre[c]);
    float sum = 0.f;
    #pragma unroll
    for (int c = 0; c < 20; ++c) { pre[c] = __expf(pre[c] - mx); sum += pre[c]; }
    float inv = 1.f / sum;
    #pragma unroll
    for (int c = 0; c < 20; ++c) out[n * 20 + c] = pre[c] * inv;
}

extern "C" void kernel_launch(void* const* d_in, const int* in_sizes, int n_in,
                              void* d_out, int out_size, void* d_ws, size_t ws_size,
                              hipStream_t stream) {
    const float* x   = (const float*)d_in[0];
    const float* ew  = (const float*)d_in[1];
    const int*   src = (const int*)d_in[2];
    const int*   dst = (const int*)d_in[3];
    const int*   ids = (const int*)d_in[4];
    const float* W1 = (const float*)d_in[5];  const float* b1 = (const float*)d_in[6];
    const float* W2 = (const float*)d_in[7];  const float* b2 = (const float*)d_in[8];
    const float* g1 = (const float*)d_in[9];  const float* be1 = (const float*)d_in[10];
    const float* m1 = (const float*)d_in[11]; const float* v1 = (const float*)d_in[12];
    const float* W3 = (const float*)d_in[13]; const float* b3 = (const float*)d_in[14];
    const float* W4 = (const float*)d_in[15]; const float* b4 = (const float*)d_in[16];
    const float* g2 = (const float*)d_in[17]; const float* be2 = (const float*)d_in[18];
    const float* m2 = (const float*)d_in[19]; const float* v2 = (const float*)d_in[20];
    const float* W5 = (const float*)d_in[21]; const float* b5 = (const float*)d_in[22];
    float* out = (float*)d_out;

    // workspace layout (~40 MB)
    char* p = (char*)d_ws;
    float*  S    = (float*)p;  p += (size_t)NN * 8 * 4;
    ushort* T    = (ushort*)p; p += (size_t)NN * 64 * 2;
    float*  AX   = (float*)p;  p += (size_t)NN * 4 * 4;
    int*    rp   = (int*)p;    p += (size_t)(NN + 16) * 4;
    int*    hcnt = (int*)p;    p += (size_t)GB * NBF * 4;    // 3.2 MB
    int*    tot  = (int*)p;    p += 1024 * 4;
    int*    bo   = (int*)p;    p += 1024 * 4;
    int2*   cB   = (int2*)p;   p += (size_t)NE * 8;
    int2*   cE   = (int2*)p;   p += (size_t)NE * 8;
    unsigned* MXE1 = (unsigned*)p; p += 256 * 4;
    unsigned* MXE2 = (unsigned*)p; p += 512 * 4;
    float*  HW3  = (float*)p;  p += 512 * 4;
    float*  HW5  = (float*)p;  p += 256 * 4;
    ushort* W2t  = (ushort*)p; p += 1024 * 2;
    ushort* W4t  = (ushort*)p; p += 4096 * 2;

    const int BS = 256;
    const int gN = (NN + BS - 1) / BS;

    // ---- CSR build (no global atomics) + weight prep ----
    hipMemsetAsync(MXE1, 0, 768 * 4, stream);
    hipLaunchKernelGGL(k_wprep, dim3(1), dim3(BS), 0, stream, W2, W4, W2t, W4t);
    hipLaunchKernelGGL(k_bhist, dim3(GB), dim3(BS), 0, stream, dst, hcnt);
    hipLaunchKernelGGL(k_bbase1, dim3(NBF), dim3(BS), 0, stream, hcnt, tot);
    hipLaunchKernelGGL(k_bbase2, dim3(1), dim3(1024), 0, stream, tot, bo);
    hipLaunchKernelGGL(k_bfill, dim3(GB), dim3(BS), 0, stream, src, dst, ew, ids, hcnt, bo, cB);
    hipLaunchKernelGGL(k_insort, dim3(NBF), dim3(512), 0, stream, bo, cB, rp, cE);

    // ---- fused S + aggX gather ----
    hipLaunchKernelGGL(k_gSX, dim3(gN), dim3(BS), 0, stream, x, rp, cE, S, AX);

    // ---- layers 1+2 (MFMA): tmp2(T) = relu(AX@W1+b1)@W2 ----
    hipLaunchKernelGGL(k_l12m, dim3(NN / 64), dim3(BS), 0, stream, AX, W1, b1, W2t, T);
    hipLaunchKernelGGL(k_gpool<5>, dim3(NN / 64), dim3(BS), 0, stream, T, rp, cE, ids, b2, g1, be1, m1, v1, MXE1);

    // ---- layers 3+4 (MFMA): HW3 = dec(MXE1)@W3; tmp4(T) = relu(S@HW3+b3)@W4 ----
    hipLaunchKernelGGL(k_dechw3, dim3(1), dim3(512), 0, stream, MXE1, W3, HW3);
    hipLaunchKernelGGL(k_l34m, dim3(NN / 64), dim3(BS), 0, stream, S, HW3, b3, W4t, T);
    hipLaunchKernelGGL(k_gpool<6>, dim3(NN / 32), dim3(BS), 0, stream, T, rp, cE, ids, b4, g2, be2, m2, v2, MXE2);

    // ---- layer 5 (collapsed): HW5 = dec(MXE2)@W5; out = softmax(S@HW5+b5) ----
    hipLaunchKernelGGL(k_dechw5, dim3(1), dim3(512), 0, stream, MXE2, W5, HW5);
    hipLaunchKernelGGL(k_out, dim3(gN), dim3(BS), 0, stream, S, HW5, b5, out);
}

// Round 9
// 259.006 us; speedup vs baseline: 5.9926x; 1.0583x over previous
//
#include <hip/hip_runtime.h>

#define NN 80000
#define NE 1280000
#define NGR 8
#define BN_EPS 1e-3f
#define NBF 625     // fine dst-buckets (128 nodes each; 625*128 == NN)
#define GB 1280     // blocks for bhist/bfill
#define CHK 1000    // edges per block (GB*CHK == NE)

typedef unsigned short ushort;
typedef __attribute__((ext_vector_type(8))) short bf16x8;
typedef __attribute__((ext_vector_type(4))) float f32x4;

// ---------------- order-preserving float <-> unsigned encoding ----------------
__device__ __forceinline__ unsigned enc_f(float f) {
    unsigned b = __float_as_uint(f);
    return (f >= 0.f) ? (b | 0x80000000u) : ~b;
}
__device__ __forceinline__ float dec_f(unsigned u) {
    return (u & 0x80000000u) ? __uint_as_float(u & 0x7FFFFFFFu) : __uint_as_float(~u);
}
// fp32 -> bf16 (round-to-nearest-even)
__device__ __forceinline__ ushort f2bf(float f) {
    unsigned u = __float_as_uint(f);
    unsigned r = u + 0x7FFFu + ((u >> 16) & 1u);
    return (ushort)(r >> 16);
}
// 8 bf16 (16B) fused-multiply-accumulate into fp32 acc[8]
__device__ __forceinline__ void fma8(float* acc, const ushort* p, float w) {
    uint4 q = *(const uint4*)p;
    acc[0] += w * __uint_as_float((q.x & 0xFFFFu) << 16);
    acc[1] += w * __uint_as_float(q.x & 0xFFFF0000u);
    acc[2] += w * __uint_as_float((q.y & 0xFFFFu) << 16);
    acc[3] += w * __uint_as_float(q.y & 0xFFFF0000u);
    acc[4] += w * __uint_as_float((q.z & 0xFFFFu) << 16);
    acc[5] += w * __uint_as_float(q.z & 0xFFFF0000u);
    acc[6] += w * __uint_as_float((q.w & 0xFFFFu) << 16);
    acc[7] += w * __uint_as_float(q.w & 0xFFFF0000u);
}

// ================= CSR build: counting sort w/ precomputed bases =================
__global__ __launch_bounds__(256) void k_bhist(const int* __restrict__ dst,
                                               int* __restrict__ hcnt) {
    __shared__ int lh[NBF];
    for (int i = threadIdx.x; i < NBF; i += 256) lh[i] = 0;
    __syncthreads();
    int e0 = blockIdx.x * CHK;
    for (int e = e0 + threadIdx.x; e < e0 + CHK; e += 256)
        atomicAdd(&lh[dst[e] >> 7], 1);
    __syncthreads();
    int* row = hcnt + (size_t)blockIdx.x * NBF;
    for (int i = threadIdx.x; i < NBF; i += 256) row[i] = lh[i];
}

__global__ __launch_bounds__(256) void k_bbase1(int* __restrict__ hcnt,
                                                int* __restrict__ tot) {
    __shared__ int sm[256];
    int bin = blockIdx.x, t = threadIdx.x;
    int v[5];
    int s = 0;
    #pragma unroll
    for (int j = 0; j < 5; ++j) {
        v[j] = hcnt[(size_t)(t * 5 + j) * NBF + bin];
        s += v[j];
    }
    sm[t] = s;
    __syncthreads();
    #pragma unroll
    for (int off = 1; off < 256; off <<= 1) {
        int u = (t >= off) ? sm[t - off] : 0;
        __syncthreads();
        sm[t] += u;
        __syncthreads();
    }
    int run = sm[t] - s;
    if (t == 255) tot[bin] = sm[255];
    #pragma unroll
    for (int j = 0; j < 5; ++j) {
        hcnt[(size_t)(t * 5 + j) * NBF + bin] = run;
        run += v[j];
    }
}

// scan of 625 bin totals -> bo, PLUS bf16 weight prep (merged to save a launch)
__global__ __launch_bounds__(1024) void k_bbase2w(const int* __restrict__ tot,
                                                  int* __restrict__ bo,
                                                  const float* __restrict__ W2,
                                                  const float* __restrict__ W4,
                                                  ushort* __restrict__ W2t,
                                                  ushort* __restrict__ W4t) {
    __shared__ int sm[1024];
    int t = threadIdx.x;
    int v = (t < NBF) ? tot[t] : 0;
    sm[t] = v;
    __syncthreads();
    #pragma unroll
    for (int off = 1; off < 1024; off <<= 1) {
        int u = (t >= off) ? sm[t - off] : 0;
        __syncthreads();
        sm[t] += u;
        __syncthreads();
    }
    if (t < NBF) bo[t] = sm[t] - v;
    if (t == 0) bo[NBF] = NE;
    // weight prep
    {
        int f = t >> 5, k = t & 31;               // t in [0,1024)
        W2t[t] = f2bf(W2[k * 32 + f]);
    }
    #pragma unroll
    for (int j = 0; j < 4; ++j) {
        int i = t + j * 1024;
        int f = i >> 6, k = i & 63;
        W4t[i] = f2bf(W4[k * 64 + f]);
    }
}

// Pass C: bucket edges; cursors precomputed (no global atomics).
// Payload: src(17b) | g(3b,@17) | dlow(7b,@20)
__global__ __launch_bounds__(256) void k_bfill(const int* __restrict__ src,
                                               const int* __restrict__ dst,
                                               const float* __restrict__ ew,
                                               const int* __restrict__ ids,
                                               const int* __restrict__ hcnt,
                                               const int* __restrict__ bo,
                                               int2* __restrict__ cB) {
    __shared__ int lcur[NBF];
    const int* row = hcnt + (size_t)blockIdx.x * NBF;
    for (int i = threadIdx.x; i < NBF; i += 256) lcur[i] = row[i] + bo[i];
    __syncthreads();
    int e0 = blockIdx.x * CHK;
    for (int e = e0 + threadIdx.x; e < e0 + CHK; e += 256) {
        int d = dst[e];
        int s = src[e];
        int pos = atomicAdd(&lcur[d >> 7], 1);
        cB[pos] = make_int2(s | (ids[s] << 17) | ((d & 127) << 20),
                            __float_as_int(ew[e]));
    }
}

// Pass D + fused gSX: one block per 128-node bucket. LDS counting sort by dlow
// -> rp, cE; then (L2-hot) re-read of this bucket's cE computes S and AX with
// 4 threads per node, partials combined via __shfl_xor within 4-lane groups.
__global__ __launch_bounds__(512) void k_insort(const int* __restrict__ bo,
                                                const int2* __restrict__ cB,
                                                const float* __restrict__ x,
                                                int* __restrict__ rp,
                                                int2* __restrict__ cE,
                                                float* __restrict__ S,
                                                float* __restrict__ AX) {
    __shared__ int lc[128];
    __shared__ int loff[128];
    __shared__ int sm[512];
    int bin = blockIdx.x, t = threadIdx.x;
    int s0 = bo[bin], s1 = bo[bin + 1];
    if (t < 128) lc[t] = 0;
    __syncthreads();
    for (int i = s0 + t; i < s1; i += 512)
        atomicAdd(&lc[(cB[i].x >> 20) & 127], 1);
    __syncthreads();
    int v = (t < 128) ? lc[t] : 0;
    sm[t] = v;
    __syncthreads();
    #pragma unroll
    for (int off = 1; off < 128; off <<= 1) {
        int u = (t >= off && t < 128) ? sm[t - off] : 0;
        __syncthreads();
        if (t < 128) sm[t] += u;
        __syncthreads();
    }
    if (t < 128) {
        loff[t] = sm[t] - v;
        rp[bin * 128 + t] = s0 + loff[t];
        lc[t] = 0;
    }
    if (bin == NBF - 1 && t == 0) rp[NN] = NE;
    __syncthreads();
    for (int i = s0 + t; i < s1; i += 512) {
        int2 a = cB[i];
        int dlow = (a.x >> 20) & 127;
        int pos = s0 + loff[dlow] + atomicAdd(&lc[dlow], 1);
        cE[pos] = make_int2((a.x & 0x1FFFF) | (((a.x >> 17) & 7) << 24), a.y);
    }
    __syncthreads();   // cE writes + lc counts final
    // ---- fused S/AX: 4 threads per node over the just-written (L2-hot) cE ----
    int n = t >> 2, q = t & 3;           // node-in-bucket, quarter
    int ne0 = s0 + loff[n];
    int ne1 = ne0 + lc[n];
    float sv[8] = {0, 0, 0, 0, 0, 0, 0, 0};
    float ax0 = 0.f, ax1 = 0.f, ax2 = 0.f;
    for (int i = ne0 + q; i < ne1; i += 4) {
        int2 a = cE[i];
        float w = __int_as_float(a.y);
        int s = a.x & 0xFFFFFF;
        int gg = a.x >> 24;
        #pragma unroll
        for (int g = 0; g < 8; ++g) sv[g] += (gg == g) ? w : 0.f;
        const float* xp = x + s * 3;
        ax0 += w * xp[0]; ax1 += w * xp[1]; ax2 += w * xp[2];
    }
    // combine the 4 partials (lanes 4n..4n+3 are consecutive in the wave)
    #pragma unroll
    for (int g = 0; g < 8; ++g) {
        sv[g] += __shfl_xor(sv[g], 1);
        sv[g] += __shfl_xor(sv[g], 2);
    }
    ax0 += __shfl_xor(ax0, 1); ax0 += __shfl_xor(ax0, 2);
    ax1 += __shfl_xor(ax1, 1); ax1 += __shfl_xor(ax1, 2);
    ax2 += __shfl_xor(ax2, 1); ax2 += __shfl_xor(ax2, 2);
    if (q == 0) {
        int node = bin * 128 + n;
        float4* Sp = (float4*)(S + (size_t)node * 8);
        Sp[0] = make_float4(sv[0], sv[1], sv[2], sv[3]);
        Sp[1] = make_float4(sv[4], sv[5], sv[6], sv[7]);
        *(float4*)(AX + (size_t)node * 4) = make_float4(ax0, ax1, ax2, 0.f);
    }
}

// ======== MFMA fused l1+l2: tmp2 = bf16(relu(AX@W1+b1)) @ bf16(W2) ========
__global__ __launch_bounds__(256) void k_l12m(const float* __restrict__ AX,
                                              const float* __restrict__ W1,
                                              const float* __restrict__ b1,
                                              const ushort* __restrict__ W2t,
                                              ushort* __restrict__ T) {
    __shared__ ushort h1s[64 * 40];
    int t = threadIdx.x;
    int nb = blockIdx.x * 64;
    {
        int f = t & 31, rr = t >> 5;
        float w0 = W1[f], w1 = W1[32 + f], w2 = W1[64 + f], bb = b1[f];
        #pragma unroll
        for (int i = 0; i < 8; ++i) {
            int n = rr + i * 8;
            float4 ax = *(const float4*)(AX + (nb + n) * 4);
            float acc = bb + ax.x * w0 + ax.y * w1 + ax.z * w2;
            h1s[n * 40 + f] = f2bf(fmaxf(acc, 0.f));
        }
    }
    __syncthreads();
    int lane = t & 63, wave = t >> 6;
    int quad = lane >> 4, col = lane & 15;
    int mtile = wave;
    bf16x8 a = *(const bf16x8*)(h1s + (mtile * 16 + col) * 40 + quad * 8);
    #pragma unroll
    for (int ntile = 0; ntile < 2; ++ntile) {
        bf16x8 b = *(const bf16x8*)(W2t + (ntile * 16 + col) * 32 + quad * 8);
        f32x4 acc = {0.f, 0.f, 0.f, 0.f};
        acc = __builtin_amdgcn_mfma_f32_16x16x32_bf16(a, b, acc, 0, 0, 0);
        #pragma unroll
        for (int r = 0; r < 4; ++r) {
            int node = nb + mtile * 16 + quad * 4 + r;
            T[node * 32 + ntile * 16 + col] = f2bf(acc[r]);
        }
    }
}

// ======== MFMA fused l3+l4 (+ integrated dechw3): ========
// HW3 = dec(MXE1)@W3 computed per block in LDS; tmp4 = bf16(relu(S@HW3+b3))@bf16(W4)
__global__ __launch_bounds__(256) void k_l34m(const float* __restrict__ S,
                                              const unsigned* __restrict__ mxe,
                                              const float* __restrict__ W3,
                                              const float* __restrict__ b3,
                                              const ushort* __restrict__ W4t,
                                              ushort* __restrict__ T) {
    __shared__ float smxs[256];
    __shared__ float HW3s[512];
    __shared__ ushort h3s[64 * 72];
    int t = threadIdx.x;
    int nb = blockIdx.x * 64;
    smxs[t] = mxe[t] ? dec_f(mxe[t]) : 0.f;
    __syncthreads();
    {   // HW3[g][f]: 512 outputs, 2 per thread
        #pragma unroll
        for (int j = 0; j < 2; ++j) {
            int i = t + j * 256;
            int g = i >> 6, f = i & 63;
            float acc = 0.f;
            #pragma unroll
            for (int k = 0; k < 32; ++k) acc += smxs[g * 32 + k] * W3[k * 64 + f];
            HW3s[i] = acc;
        }
    }
    __syncthreads();
    {
        int f = t & 63, rr = t >> 6;
        float hwc[8];
        #pragma unroll
        for (int g = 0; g < 8; ++g) hwc[g] = HW3s[g * 64 + f];
        float bb = b3[f];
        #pragma unroll
        for (int i = 0; i < 16; ++i) {
            int n = rr + i * 4;
            const float4* sp = (const float4*)(S + (size_t)(nb + n) * 8);
            float4 s0 = sp[0], s1 = sp[1];
            float acc = bb + s0.x * hwc[0] + s0.y * hwc[1] + s0.z * hwc[2] +
                        s0.w * hwc[3] + s1.x * hwc[4] + s1.y * hwc[5] +
                        s1.z * hwc[6] + s1.w * hwc[7];
            h3s[n * 72 + f] = f2bf(fmaxf(acc, 0.f));
        }
    }
    __syncthreads();
    int lane = t & 63, wave = t >> 6;
    int quad = lane >> 4, col = lane & 15;
    int mtile = wave;
    bf16x8 a0 = *(const bf16x8*)(h3s + (mtile * 16 + col) * 72 + quad * 8);
    bf16x8 a1 = *(const bf16x8*)(h3s + (mtile * 16 + col) * 72 + 32 + quad * 8);
    #pragma unroll
    for (int ntile = 0; ntile < 4; ++ntile) {
        bf16x8 b0 = *(const bf16x8*)(W4t + (ntile * 16 + col) * 64 + quad * 8);
        bf16x8 b1v = *(const bf16x8*)(W4t + (ntile * 16 + col) * 64 + 32 + quad * 8);
        f32x4 acc = {0.f, 0.f, 0.f, 0.f};
        acc = __builtin_amdgcn_mfma_f32_16x16x32_bf16(a0, b0, acc, 0, 0, 0);
        acc = __builtin_amdgcn_mfma_f32_16x16x32_bf16(a1, b1v, acc, 0, 0, 0);
        #pragma unroll
        for (int r = 0; r < 4; ++r) {
            int node = nb + mtile * 16 + quad * 4 + r;
            T[node * 64 + ntile * 16 + col] = f2bf(acc[r]);
        }
    }
}

// ---- fused gather (bf16 rows) + bias + relu + BN + per-graph max pool ----
// 4-way unrolled edge loop for memory-level parallelism
template <int LOGF>
__global__ __launch_bounds__(256) void k_gpool(const ushort* __restrict__ th,
                                               const int* __restrict__ rp,
                                               const int2* __restrict__ cE,
                                               const int* __restrict__ ids,
                                               const float* __restrict__ b,
                                               const float* __restrict__ g,
                                               const float* __restrict__ be,
                                               const float* __restrict__ m,
                                               const float* __restrict__ v,
                                               unsigned* __restrict__ mxe) {
    const int F = 1 << LOGF;
    const int CPN = F >> 3;
    const int NPB = 256 / CPN;
    __shared__ unsigned lmx[NGR * F];
    for (int i = threadIdx.x; i < NGR * F; i += 256) lmx[i] = 0u;
    __syncthreads();
    int c = threadIdx.x & (CPN - 1);
    int n = blockIdx.x * NPB + (threadIdx.x >> (LOGF - 3));
    if (n < NN) {
        int e0 = rp[n], e1 = rp[n + 1];
        float a0[8] = {0, 0, 0, 0, 0, 0, 0, 0};
        float a1[8] = {0, 0, 0, 0, 0, 0, 0, 0};
        float a2[8] = {0, 0, 0, 0, 0, 0, 0, 0};
        float a3[8] = {0, 0, 0, 0, 0, 0, 0, 0};
        int i = e0;
        for (; i + 4 <= e1; i += 4) {
            int2 q0 = cE[i], q1 = cE[i + 1], q2 = cE[i + 2], q3 = cE[i + 3];
            fma8(a0, th + (((size_t)(q0.x & 0xFFFFFF)) << LOGF) + (c << 3), __int_as_float(q0.y));
            fma8(a1, th + (((size_t)(q1.x & 0xFFFFFF)) << LOGF) + (c << 3), __int_as_float(q1.y));
            fma8(a2, th + (((size_t)(q2.x & 0xFFFFFF)) << LOGF) + (c << 3), __int_as_float(q2.y));
            fma8(a3, th + (((size_t)(q3.x & 0xFFFFFF)) << LOGF) + (c << 3), __int_as_float(q3.y));
        }
        for (; i < e1; ++i) {
            int2 q0 = cE[i];
            fma8(a0, th + (((size_t)(q0.x & 0xFFFFFF)) << LOGF) + (c << 3), __int_as_float(q0.y));
        }
        int gg = ids[n];
        #pragma unroll
        for (int j = 0; j < 8; ++j) {
            int f = (c << 3) + j;
            float scale = g[f] * rsqrtf(v[f] + BN_EPS);
            float h = fmaxf((a0[j] + a1[j]) + (a2[j] + a3[j]) + b[f], 0.f);
            float val = (h - m[f]) * scale + be[f];
            atomicMax(&lmx[gg * F + f], enc_f(val));
        }
    }
    __syncthreads();
    for (int i = threadIdx.x; i < NGR * F; i += 256) {
        unsigned u = lmx[i];
        if (u) atomicMax(&mxe[i], u);
    }
}

// ---- out = softmax(S @ (dec(MXE2)@W5) + b5), HW5 computed per block ----
__global__ __launch_bounds__(256) void k_out(const float* __restrict__ S,
                                             const unsigned* __restrict__ mxe,
                                             const float* __restrict__ W5,
                                             const float* __restrict__ b5,
                                             float* __restrict__ out) {
    __shared__ float smxs[512];
    __shared__ float hw[160];
    __shared__ float bb[20];
    int t = threadIdx.x;
    smxs[t] = mxe[t] ? dec_f(mxe[t]) : 0.f;
    smxs[t + 256] = mxe[t + 256] ? dec_f(mxe[t + 256]) : 0.f;
    if (t < 20) bb[t] = b5[t];
    __syncthreads();
    if (t < 160) {
        int g = t / 20, c = t % 20;
        float acc = 0.f;
        #pragma unroll
        for (int k = 0; k < 64; ++k) acc += smxs[g * 64 + k] * W5[k * 20 + c];
        hw[t] = acc;
    }
    __syncthreads();
    int n = blockIdx.x * 256 + t;
    if (n >= NN) return;
    const float4* sp = (const float4*)(S + (size_t)n * 8);
    float4 s0 = sp[0], s1 = sp[1];
    float sv[8] = {s0.x, s0.y, s0.z, s0.w, s1.x, s1.y, s1.z, s1.w};
    float pre[20];
    #pragma unroll
    for (int c = 0; c < 20; ++c) {
        float acc = bb[c];
        #pragma unroll
        for (int g = 0; g < 8; ++g) acc += sv[g] * hw[g * 20 + c];
        pre[c] = acc;
    }
    float mx = pre[0];
    #pragma unroll
    for (int c = 1; c < 20; ++c) mx = fmaxf(mx, pre[c]);
    float sum = 0.f;
    #pragma unroll
    for (int c = 0; c < 20; ++c) { pre[c] = __expf(pre[c] - mx); sum += pre[c]; }
    float inv = 1.f / sum;
    #pragma unroll
    for (int c = 0; c < 20; ++c) out[n * 20 + c] = pre[c] * inv;
}

extern "C" void kernel_launch(void* const* d_in, const int* in_sizes, int n_in,
                              void* d_out, int out_size, void* d_ws, size_t ws_size,
                              hipStream_t stream) {
    const float* x   = (const float*)d_in[0];
    const float* ew  = (const float*)d_in[1];
    const int*   src = (const int*)d_in[2];
    const int*   dst = (const int*)d_in[3];
    const int*   ids = (const int*)d_in[4];
    const float* W1 = (const float*)d_in[5];  const float* b1 = (const float*)d_in[6];
    const float* W2 = (const float*)d_in[7];  const float* b2 = (const float*)d_in[8];
    const float* g1 = (const float*)d_in[9];  const float* be1 = (const float*)d_in[10];
    const float* m1 = (const float*)d_in[11]; const float* v1 = (const float*)d_in[12];
    const float* W3 = (const float*)d_in[13]; const float* b3 = (const float*)d_in[14];
    const float* W4 = (const float*)d_in[15]; const float* b4 = (const float*)d_in[16];
    const float* g2 = (const float*)d_in[17]; const float* be2 = (const float*)d_in[18];
    const float* m2 = (const float*)d_in[19]; const float* v2 = (const float*)d_in[20];
    const float* W5 = (const float*)d_in[21]; const float* b5 = (const float*)d_in[22];
    float* out = (float*)d_out;

    // workspace layout (~40 MB)
    char* p = (char*)d_ws;
    float*  S    = (float*)p;  p += (size_t)NN * 8 * 4;
    ushort* T    = (ushort*)p; p += (size_t)NN * 64 * 2;
    float*  AX   = (float*)p;  p += (size_t)NN * 4 * 4;
    int*    rp   = (int*)p;    p += (size_t)(NN + 16) * 4;
    int*    hcnt = (int*)p;    p += (size_t)GB * NBF * 4;    // 3.2 MB
    int*    tot  = (int*)p;    p += 1024 * 4;
    int*    bo   = (int*)p;    p += 1024 * 4;
    int2*   cB   = (int2*)p;   p += (size_t)NE * 8;
    int2*   cE   = (int2*)p;   p += (size_t)NE * 8;
    unsigned* MXE1 = (unsigned*)p; p += 256 * 4;
    unsigned* MXE2 = (unsigned*)p; p += 512 * 4;
    ushort* W2t  = (ushort*)p; p += 1024 * 2;
    ushort* W4t  = (ushort*)p; p += 4096 * 2;

    const int BS = 256;
    const int gN = (NN + BS - 1) / BS;

    // ---- CSR build (no global atomics) ----
    hipMemsetAsync(MXE1, 0, 768 * 4, stream);
    hipLaunchKernelGGL(k_bhist, dim3(GB), dim3(BS), 0, stream, dst, hcnt);
    hipLaunchKernelGGL(k_bbase1, dim3(NBF), dim3(BS), 0, stream, hcnt, tot);
    hipLaunchKernelGGL(k_bbase2w, dim3(1), dim3(1024), 0, stream, tot, bo, W2, W4, W2t, W4t);
    hipLaunchKernelGGL(k_bfill, dim3(GB), dim3(BS), 0, stream, src, dst, ew, ids, hcnt, bo, cB);
    hipLaunchKernelGGL(k_insort, dim3(NBF), dim3(512), 0, stream, bo, cB, x, rp, cE, S, AX);

    // ---- layers 1+2 (MFMA): tmp2(T) = relu(AX@W1+b1)@W2 ----
    hipLaunchKernelGGL(k_l12m, dim3(NN / 64), dim3(BS), 0, stream, AX, W1, b1, W2t, T);
    hipLaunchKernelGGL(k_gpool<5>, dim3(NN / 64), dim3(BS), 0, stream, T, rp, cE, ids, b2, g1, be1, m1, v1, MXE1);

    // ---- layers 3+4 (MFMA, dechw3 integrated): tmp4(T) = relu(S@HW3+b3)@W4 ----
    hipLaunchKernelGGL(k_l34m, dim3(NN / 64), dim3(BS), 0, stream, S, MXE1, W3, b3, W4t, T);
    hipLaunchKernelGGL(k_gpool<6>, dim3(NN / 32), dim3(BS), 0, stream, T, rp, cE, ids, b4, g2, be2, m2, v2, MXE2);

    // ---- layer 5 (collapsed, dechw5 integrated): out = softmax(S@HW5+b5) ----
    hipLaunchKernelGGL(k_out, dim3(gN), dim3(BS), 0, stream, S, MXE2, W5, b5, out);
}